// Round 1
// baseline (997.204 us; speedup 1.0000x reference)
//
#include <hip/hip_runtime.h>
#include <cmath>

#define BN 16
#define CDIM 64
#define TOT 8192
#define KNB 20
#define CN 512
#define NSTEPS 8
#define WPB 16           // walkers per block (4 waves x 4 groups)
#define BPB 32           // blocks per batch (CN / WPB)

// butterfly sum across the 16-lane group (xor masks 1,2,4,8 stay in-group)
__device__ __forceinline__ float gred16(float v) {
  v += __shfl_xor(v, 1, 64);
  v += __shfl_xor(v, 2, 64);
  v += __shfl_xor(v, 4, 64);
  v += __shfl_xor(v, 8, 64);
  return v;
}

__global__ __launch_bounds__(256) void transpose_x(const float* __restrict__ x,
                                                   float* __restrict__ xt) {
  __shared__ float tile[CDIM][65];
  const int b  = blockIdx.x >> 7;          // 128 tiles per batch
  const int t0 = (blockIdx.x & 127) << 6;  // 64 t per tile
  const int tid = threadIdx.x;
#pragma unroll
  for (int i = 0; i < 16; ++i) {
    int idx = tid + i * 256;
    int cc = idx >> 6, tt = idx & 63;
    tile[cc][tt] = x[((size_t)b * CDIM + cc) * TOT + t0 + tt];
  }
  __syncthreads();
#pragma unroll
  for (int i = 0; i < 16; ++i) {
    int idx = tid + i * 256;
    int tt = idx >> 6, cc = idx & 63;
    xt[((size_t)b * TOT + t0 + tt) * CDIM + cc] = tile[cc][tt];
  }
}

__global__ __launch_bounds__(256) void walk_kernel(
    const float* __restrict__ xt, const int* __restrict__ adj, const int* __restrict__ cur,
    const float* __restrict__ agent_w, const float* __restrict__ agent_gamma,
    const float* __restrict__ agent_beta, const float* __restrict__ agent_mean,
    const float* __restrict__ agent_var, const float* __restrict__ mom_w,
    const float* __restrict__ mom_gamma, const float* __restrict__ mom_beta,
    const float* __restrict__ mom_mean, const float* __restrict__ mom_var,
    float* __restrict__ out, float* __restrict__ sbuf, unsigned int* __restrict__ cnt) {
  const int tid  = threadIdx.x;
  const int lane = tid & 63;
  const int wv   = tid >> 6;
  const int g    = lane >> 4;   // group within wave (one walker per group)
  const int L    = lane & 15;   // lane within group
  // XCD swizzle: batch b lives on XCD b&7 so its 2.6MB working set stays in one L2
  const int b     = (blockIdx.x & 7) + (((blockIdx.x >> 8) & 1) << 3);
  const int chunk = (blockIdx.x >> 3) & 31;
  const int n     = chunk * WPB + wv * 4 + g;  // walker index within batch
  const int c0    = L << 2;                    // channels c0..c0+3

  const float4 aw1  = *(const float4*)(agent_w + c0);
  const float4 aw2  = *(const float4*)(agent_w + 64 + c0);
  const float4 mw0a = *(const float4*)(mom_w + c0);
  const float4 mw0b = *(const float4*)(mom_w + 64 + c0);
  const float4 mw1a = *(const float4*)(mom_w + 128 + c0);
  const float4 mw1b = *(const float4*)(mom_w + 192 + c0);
  const float amean  = agent_mean[0];
  const float abeta  = agent_beta[0];
  const float ainv   = agent_gamma[0] / sqrtf(agent_var[0] + 1e-5f);
  const float m0mean = mom_mean[0], m1mean = mom_mean[1];
  const float m0inv  = mom_gamma[0] / sqrtf(mom_var[0] + 1e-5f);
  const float m1inv  = mom_gamma[1] / sqrtf(mom_var[1] + 1e-5f);
  const float m0beta = mom_beta[0], m1beta = mom_beta[1];

  const float* xb   = xt + (size_t)b * TOT * CDIM;
  const int*   adjb = adj + (size_t)b * TOT * KNB;

  int t = cur[b * CN + n];
  float4 pf = *(const float4*)(xb + (size_t)t * CDIM + c0);
  float4 cf = pf;
  float4 u  = make_float4(0.f, 0.f, 0.f, 0.f);

#pragma unroll 1
  for (int s = 0; s < NSTEPS; ++s) {
    float n1 = 0.f;
    if (s > 0) {
      // ---- momentum attention: mlog for THIS walker ----
      float p0 = cf.x * mw0a.x + cf.y * mw0a.y + cf.z * mw0a.z + cf.w * mw0a.w +
                 pf.x * mw0b.x + pf.y * mw0b.y + pf.z * mw0b.z + pf.w * mw0b.w;
      float p1 = cf.x * mw1a.x + cf.y * mw1a.y + cf.z * mw1a.z + cf.w * mw1a.w +
                 pf.x * mw1b.x + pf.y * mw1b.y + pf.z * mw1b.z + pf.w * mw1b.w;
      p0 = gred16(p0);
      p1 = gred16(p1);
      float mlog0 = (p0 - m0mean) * m0inv + m0beta;
      float mlog1 = (p1 - m1mean) * m1inv + m1beta;
      float mx = fmaxf(mlog0, mlog1);
      float e0 = expf(mlog0 - mx), e1 = expf(mlog1 - mx);
      float sinv = 1.0f / (e0 + e1);
      float S0 = e0 * sinv, S1 = e1 * sinv;
      // ---- publish S, barrier across the batch's 32 blocks, read scrambled coeffs ----
      float* sb = sbuf + ((size_t)(b * NSTEPS + s) << 10);  // [o][m] = 1024 floats
      if (L == 0) {
        __hip_atomic_store(sb + n, S0, __ATOMIC_RELAXED, __HIP_MEMORY_SCOPE_AGENT);
        __hip_atomic_store(sb + CN + n, S1, __ATOMIC_RELAXED, __HIP_MEMORY_SCOPE_AGENT);
      }
      __threadfence();
      __syncthreads();
      unsigned int* c = cnt + (b * NSTEPS + s);
      if (tid == 0) {
        __hip_atomic_fetch_add(c, 1u, __ATOMIC_ACQ_REL, __HIP_MEMORY_SCOPE_AGENT);
        while (__hip_atomic_load(c, __ATOMIC_ACQUIRE, __HIP_MEMORY_SCOPE_AGENT) < BPB) {
          __builtin_amdgcn_s_sleep(4);
        }
      }
      __syncthreads();
      __threadfence();
      // faithful torch .view scramble: coeff e of walker n = S[(2n+e)/512][(2n+e)%512]
      float A0 = __hip_atomic_load(sb + 2 * n, __ATOMIC_RELAXED, __HIP_MEMORY_SCOPE_AGENT);
      float A1 = __hip_atomic_load(sb + 2 * n + 1, __ATOMIC_RELAXED, __HIP_MEMORY_SCOPE_AGENT);
      pf.x = A0 * cf.x + A1 * pf.x;
      pf.y = A0 * cf.y + A1 * pf.y;
      pf.z = A0 * cf.z + A1 * pf.z;
      pf.w = A0 * cf.w + A1 * pf.w;
      u.x = cf.x - pf.x; u.y = cf.y - pf.y; u.z = cf.z - pf.z; u.w = cf.w - pf.w;
      n1 = sqrtf(gred16(u.x * u.x + u.y * u.y + u.z * u.z + u.w * u.w));
    }
    float pw = gred16(pf.x * aw2.x + pf.y * aw2.y + pf.z * aw2.z + pf.w * aw2.w);

    // neighbor indices for current node t (lane L holds j=L; lanes 0..3 also j=16..19)
    const int rowbase = t * KNB;
    int i1 = adjb[rowbase + L];
    int i2 = (L < KNB - 16) ? adjb[rowbase + 16 + L] : 0;

    float  bestp = -3.4e38f;
    int    bestt = 0;
    float4 bestv = make_float4(0.f, 0.f, 0.f, 0.f);
#pragma unroll
    for (int j = 0; j < KNB; ++j) {
      int src = (lane & 48) | (j & 15);
      int tj  = __shfl((j < 16) ? i1 : i2, src, 64);
      const float4 v = *(const float4*)(xb + (size_t)tj * CDIM + c0);
      float pa = v.x * aw1.x + v.y * aw1.y + v.z * aw1.z + v.w * aw1.w;
      float su = 0.f, sn = 0.f;
      if (s > 0) {
        float tx = v.x - cf.x, ty = v.y - cf.y, tz = v.z - cf.z, tw = v.w - cf.w;
        su = tx * u.x + ty * u.y + tz * u.z + tw * u.w;
        sn = tx * tx + ty * ty + tz * tz + tw * tw;
      }
      pa = gred16(pa);
      float logit = (pa + pw - amean) * ainv + abeta;
      float p;
      if (s > 0) {
        su = gred16(su);
        sn = gred16(sn);
        float den  = fmaxf(n1 * sqrtf(sn), 1e-8f);
        float cosv = su / den;
        float dfac = fminf(fmaxf(1.0f + cosv, 0.0f), 1.0f);
        p = logit * dfac;
      } else {
        p = logit;
      }
      // strict > keeps first-occurrence argmax like jnp.argmax; group-uniform cond
      if (p > bestp) { bestp = p; bestt = tj; bestv = v; }
    }
    cf = bestv;
    t  = bestt;
    // out[b][c][n][s], channel stride = CN*NSTEPS = 4096 floats
    float* op = out + ((size_t)(b * CDIM + c0) * CN + n) * NSTEPS + s;
    op[0]     = cf.x;
    op[4096]  = cf.y;
    op[8192]  = cf.z;
    op[12288] = cf.w;
  }
}

extern "C" void kernel_launch(void* const* d_in, const int* in_sizes, int n_in,
                              void* d_out, int out_size, void* d_ws, size_t ws_size,
                              hipStream_t stream) {
  (void)in_sizes; (void)n_in; (void)out_size; (void)ws_size;
  // setup_inputs order: xyz(0,unused), x(1), adj(2), cur(3), agent_w(4), agent_gamma(5),
  // agent_beta(6), agent_mean(7), agent_var(8), mom_w(9), mom_gamma(10), mom_beta(11),
  // mom_mean(12), mom_var(13)
  const float* x          = (const float*)d_in[1];
  const int*   adj        = (const int*)d_in[2];
  const int*   cur        = (const int*)d_in[3];
  const float* agent_w    = (const float*)d_in[4];
  const float* agent_gamma= (const float*)d_in[5];
  const float* agent_beta = (const float*)d_in[6];
  const float* agent_mean = (const float*)d_in[7];
  const float* agent_var  = (const float*)d_in[8];
  const float* mom_w      = (const float*)d_in[9];
  const float* mom_gamma  = (const float*)d_in[10];
  const float* mom_beta   = (const float*)d_in[11];
  const float* mom_mean   = (const float*)d_in[12];
  const float* mom_var    = (const float*)d_in[13];
  float* out = (float*)d_out;

  char* ws = (char*)d_ws;
  const size_t xt_bytes   = (size_t)BN * TOT * CDIM * sizeof(float);   // 33.5 MB
  const size_t sbuf_bytes = (size_t)BN * NSTEPS * 2 * CN * sizeof(float);
  float*        xt   = (float*)ws;
  float*        sbuf = (float*)(ws + xt_bytes);
  unsigned int* cnt  = (unsigned int*)(ws + xt_bytes + sbuf_bytes);

  hipMemsetAsync(cnt, 0, BN * NSTEPS * sizeof(unsigned int), stream);
  transpose_x<<<BN * (TOT / 64), 256, 0, stream>>>(x, xt);
  walk_kernel<<<BN * BPB, 256, 0, stream>>>(xt, adj, cur, agent_w, agent_gamma, agent_beta,
                                            agent_mean, agent_var, mom_w, mom_gamma, mom_beta,
                                            mom_mean, mom_var, out, sbuf, cnt);
}

// Round 2
// 260.530 us; speedup vs baseline: 3.8276x; 3.8276x over previous
//
#include <hip/hip_runtime.h>
#include <cmath>

#define BN 16
#define CDIM 64
#define TOT 8192
#define KNB 20
#define CN 512
#define NSTEPS 8
#define WPB 16           // walkers per block (4 waves x 4 groups)
#define BPB 32           // blocks per batch (CN / WPB)

// DPP add: v += lane-permuted(v). All patterns stay within the 16-lane row.
template <int CTRL>
__device__ __forceinline__ float dpp_add(float v) {
  int o = __builtin_amdgcn_update_dpp(0, __float_as_int(v), CTRL, 0xF, 0xF, true);
  return v + __int_as_float(o);
}

// butterfly sum across the 16-lane group — pure VALU (no DS), bitwise identical
// tree to the shfl_xor 1/2/4/8 version (commutative pairwise adds).
__device__ __forceinline__ float gred16(float v) {
  v = dpp_add<0xB1>(v);   // quad_perm(1,0,3,2)  == xor 1
  v = dpp_add<0x4E>(v);   // quad_perm(2,3,0,1)  == xor 2
  v = dpp_add<0x141>(v);  // row_half_mirror     == partner quad
  v = dpp_add<0x140>(v);  // row_mirror          == partner half
  return v;
}

__global__ __launch_bounds__(256) void transpose_x(const float* __restrict__ x,
                                                   float* __restrict__ xt) {
  __shared__ float tile[CDIM][65];
  const int b  = blockIdx.x >> 7;          // 128 tiles per batch
  const int t0 = (blockIdx.x & 127) << 6;  // 64 t per tile
  const int tid = threadIdx.x;
#pragma unroll
  for (int i = 0; i < 16; ++i) {
    int idx = tid + i * 256;
    int cc = idx >> 6, tt = idx & 63;
    tile[cc][tt] = x[((size_t)b * CDIM + cc) * TOT + t0 + tt];
  }
  __syncthreads();
#pragma unroll
  for (int i = 0; i < 16; ++i) {
    int idx = tid + i * 256;
    int tt = idx >> 6, cc = idx & 63;
    xt[((size_t)b * TOT + t0 + tt) * CDIM + cc] = tile[cc][tt];
  }
}

__global__ __launch_bounds__(256) void walk_kernel(
    const float* __restrict__ xt, const int* __restrict__ adj, const int* __restrict__ cur,
    const float* __restrict__ agent_w, const float* __restrict__ agent_gamma,
    const float* __restrict__ agent_beta, const float* __restrict__ agent_mean,
    const float* __restrict__ agent_var, const float* __restrict__ mom_w,
    const float* __restrict__ mom_gamma, const float* __restrict__ mom_beta,
    const float* __restrict__ mom_mean, const float* __restrict__ mom_var,
    float* __restrict__ out, float* __restrict__ sbuf, unsigned int* __restrict__ cnt) {
  const int tid  = threadIdx.x;
  const int lane = tid & 63;
  const int wv   = tid >> 6;
  const int g    = lane >> 4;   // group within wave (one walker per group)
  const int L    = lane & 15;   // lane within group
  // XCD swizzle: batch b lives on XCD b&7 so its 2.6MB working set stays in one L2
  const int b     = (blockIdx.x & 7) + (((blockIdx.x >> 8) & 1) << 3);
  const int chunk = (blockIdx.x >> 3) & 31;
  const int n     = chunk * WPB + wv * 4 + g;  // walker index within batch
  const int c0    = L << 2;                    // channels c0..c0+3

  const float4 aw1  = *(const float4*)(agent_w + c0);
  const float4 aw2  = *(const float4*)(agent_w + 64 + c0);
  const float4 mw0a = *(const float4*)(mom_w + c0);
  const float4 mw0b = *(const float4*)(mom_w + 64 + c0);
  const float4 mw1a = *(const float4*)(mom_w + 128 + c0);
  const float4 mw1b = *(const float4*)(mom_w + 192 + c0);
  const float amean  = agent_mean[0];
  const float abeta  = agent_beta[0];
  const float ainv   = agent_gamma[0] / sqrtf(agent_var[0] + 1e-5f);
  const float m0mean = mom_mean[0], m1mean = mom_mean[1];
  const float m0inv  = mom_gamma[0] / sqrtf(mom_var[0] + 1e-5f);
  const float m1inv  = mom_gamma[1] / sqrtf(mom_var[1] + 1e-5f);
  const float m0beta = mom_beta[0], m1beta = mom_beta[1];

  const float* xb   = xt + (size_t)b * TOT * CDIM;
  const int*   adjb = adj + (size_t)b * TOT * KNB;

  int t = cur[b * CN + n];
  float4 pf = *(const float4*)(xb + (size_t)t * CDIM + c0);
  float4 cf = pf;
  float4 u  = make_float4(0.f, 0.f, 0.f, 0.f);

#pragma unroll 1
  for (int s = 0; s < NSTEPS; ++s) {
    float n1 = 0.f;
    if (s > 0) {
      // ---- momentum attention: mlog for THIS walker ----
      float p0 = cf.x * mw0a.x + cf.y * mw0a.y + cf.z * mw0a.z + cf.w * mw0a.w +
                 pf.x * mw0b.x + pf.y * mw0b.y + pf.z * mw0b.z + pf.w * mw0b.w;
      float p1 = cf.x * mw1a.x + cf.y * mw1a.y + cf.z * mw1a.z + cf.w * mw1a.w +
                 pf.x * mw1b.x + pf.y * mw1b.y + pf.z * mw1b.z + pf.w * mw1b.w;
      p0 = gred16(p0);
      p1 = gred16(p1);
      float mlog0 = (p0 - m0mean) * m0inv + m0beta;
      float mlog1 = (p1 - m1mean) * m1inv + m1beta;
      float mx = fmaxf(mlog0, mlog1);
      float e0 = expf(mlog0 - mx), e1 = expf(mlog1 - mx);
      float sinv = 1.0f / (e0 + e1);
      float S0 = e0 * sinv, S1 = e1 * sinv;
      // ---- publish S via MALL-coherent relaxed atomics; spin barrier, no fences ----
      float* sb = sbuf + ((size_t)(b * NSTEPS + s) << 10);  // [o][m] = 1024 floats
      if (L == 0) {
        __hip_atomic_store(sb + n, S0, __ATOMIC_RELAXED, __HIP_MEMORY_SCOPE_AGENT);
        __hip_atomic_store(sb + CN + n, S1, __ATOMIC_RELAXED, __HIP_MEMORY_SCOPE_AGENT);
      }
      // release: our sb stores have reached the coherence point before the count bump
      asm volatile("s_waitcnt vmcnt(0)" ::: "memory");
      __syncthreads();
      unsigned int* c = cnt + (b * NSTEPS + s);
      if (tid == 0) {
        __hip_atomic_fetch_add(c, 1u, __ATOMIC_RELAXED, __HIP_MEMORY_SCOPE_AGENT);
        while (__hip_atomic_load(c, __ATOMIC_RELAXED, __HIP_MEMORY_SCOPE_AGENT) < BPB) {
          __builtin_amdgcn_s_sleep(8);
        }
      }
      __syncthreads();
      // readers use relaxed AGENT atomic loads (read at MALL) — no invalidate needed
      float A0 = __hip_atomic_load(sb + 2 * n, __ATOMIC_RELAXED, __HIP_MEMORY_SCOPE_AGENT);
      float A1 = __hip_atomic_load(sb + 2 * n + 1, __ATOMIC_RELAXED, __HIP_MEMORY_SCOPE_AGENT);
      pf.x = A0 * cf.x + A1 * pf.x;
      pf.y = A0 * cf.y + A1 * pf.y;
      pf.z = A0 * cf.z + A1 * pf.z;
      pf.w = A0 * cf.w + A1 * pf.w;
      u.x = cf.x - pf.x; u.y = cf.y - pf.y; u.z = cf.z - pf.z; u.w = cf.w - pf.w;
      n1 = sqrtf(gred16(u.x * u.x + u.y * u.y + u.z * u.z + u.w * u.w));
    }
    float pw = gred16(pf.x * aw2.x + pf.y * aw2.y + pf.z * aw2.z + pf.w * aw2.w);

    // neighbor indices: 5 uniform int4 loads (row is 80B, 16B-aligned). All 16
    // lanes of the group read the same address -> 1 line; available up-front so
    // the 20 gathers below can issue ahead without a per-j shuffle dependency.
    const int4* arow = (const int4*)(adjb + (size_t)t * KNB);
    int4 q0 = arow[0], q1 = arow[1], q2 = arow[2], q3 = arow[3], q4 = arow[4];
    int idx[KNB] = {q0.x, q0.y, q0.z, q0.w, q1.x, q1.y, q1.z, q1.w,
                    q2.x, q2.y, q2.z, q2.w, q3.x, q3.y, q3.z, q3.w,
                    q4.x, q4.y, q4.z, q4.w};

    float  bestp = -3.4e38f;
    int    bestt = 0;
    float4 bestv = make_float4(0.f, 0.f, 0.f, 0.f);
#pragma unroll
    for (int j = 0; j < KNB; ++j) {
      int tj = idx[j];
      const float4 v = *(const float4*)(xb + (size_t)tj * CDIM + c0);
      float pa = v.x * aw1.x + v.y * aw1.y + v.z * aw1.z + v.w * aw1.w;
      float su = 0.f, sn = 0.f;
      if (s > 0) {
        float tx = v.x - cf.x, ty = v.y - cf.y, tz = v.z - cf.z, tw = v.w - cf.w;
        su = tx * u.x + ty * u.y + tz * u.z + tw * u.w;
        sn = tx * tx + ty * ty + tz * tz + tw * tw;
      }
      pa = gred16(pa);
      float logit = (pa + pw - amean) * ainv + abeta;
      float p;
      if (s > 0) {
        su = gred16(su);
        sn = gred16(sn);
        float den  = fmaxf(n1 * sqrtf(sn), 1e-8f);
        float cosv = su / den;
        float dfac = fminf(fmaxf(1.0f + cosv, 0.0f), 1.0f);
        p = logit * dfac;
      } else {
        p = logit;
      }
      // strict > keeps first-occurrence argmax like jnp.argmax; group-uniform cond
      if (p > bestp) { bestp = p; bestt = tj; bestv = v; }
    }
    cf = bestv;
    t  = bestt;
    // out[b][c][n][s], channel stride = CN*NSTEPS = 4096 floats
    float* op = out + ((size_t)(b * CDIM + c0) * CN + n) * NSTEPS + s;
    op[0]     = cf.x;
    op[4096]  = cf.y;
    op[8192]  = cf.z;
    op[12288] = cf.w;
  }
}

extern "C" void kernel_launch(void* const* d_in, const int* in_sizes, int n_in,
                              void* d_out, int out_size, void* d_ws, size_t ws_size,
                              hipStream_t stream) {
  (void)in_sizes; (void)n_in; (void)out_size; (void)ws_size;
  const float* x          = (const float*)d_in[1];
  const int*   adj        = (const int*)d_in[2];
  const int*   cur        = (const int*)d_in[3];
  const float* agent_w    = (const float*)d_in[4];
  const float* agent_gamma= (const float*)d_in[5];
  const float* agent_beta = (const float*)d_in[6];
  const float* agent_mean = (const float*)d_in[7];
  const float* agent_var  = (const float*)d_in[8];
  const float* mom_w      = (const float*)d_in[9];
  const float* mom_gamma  = (const float*)d_in[10];
  const float* mom_beta   = (const float*)d_in[11];
  const float* mom_mean   = (const float*)d_in[12];
  const float* mom_var    = (const float*)d_in[13];
  float* out = (float*)d_out;

  char* ws = (char*)d_ws;
  const size_t xt_bytes   = (size_t)BN * TOT * CDIM * sizeof(float);   // 33.5 MB
  const size_t sbuf_bytes = (size_t)BN * NSTEPS * 2 * CN * sizeof(float);
  float*        xt   = (float*)ws;
  float*        sbuf = (float*)(ws + xt_bytes);
  unsigned int* cnt  = (unsigned int*)(ws + xt_bytes + sbuf_bytes);

  hipMemsetAsync(cnt, 0, BN * NSTEPS * sizeof(unsigned int), stream);
  transpose_x<<<BN * (TOT / 64), 256, 0, stream>>>(x, xt);
  walk_kernel<<<BN * BPB, 256, 0, stream>>>(xt, adj, cur, agent_w, agent_gamma, agent_beta,
                                            agent_mean, agent_var, mom_w, mom_gamma, mom_beta,
                                            mom_mean, mom_var, out, sbuf, cnt);
}

// Round 3
// 209.546 us; speedup vs baseline: 4.7589x; 1.2433x over previous
//
#include <hip/hip_runtime.h>
#include <cmath>

#define BN 16
#define CDIM 64
#define TOT 8192
#define KNB 20
#define CN 512
#define NSTEPS 8
#define WPB 16           // walkers per block (4 waves x 4 groups)
#define BPB 32           // blocks per batch (CN / WPB)
#define WSTRIDE 577      // per-walker LDS out-buffer stride (64*9 + 1 pad)

// DPP add: v += lane-permuted(v). All patterns stay within the 16-lane row.
template <int CTRL>
__device__ __forceinline__ float dpp_add(float v) {
  int o = __builtin_amdgcn_update_dpp(0, __float_as_int(v), CTRL, 0xF, 0xF, true);
  return v + __int_as_float(o);
}

// butterfly sum across the 16-lane group — pure VALU, bitwise identical tree
__device__ __forceinline__ float gred16(float v) {
  v = dpp_add<0xB1>(v);   // quad_perm(1,0,3,2)  == xor 1
  v = dpp_add<0x4E>(v);   // quad_perm(2,3,0,1)  == xor 2
  v = dpp_add<0x141>(v);  // row_half_mirror     == xor 4
  v = dpp_add<0x140>(v);  // row_mirror          == xor 8
  return v;
}

__global__ __launch_bounds__(256) void transpose_x(const float* __restrict__ x,
                                                   float* __restrict__ xt,
                                                   unsigned int* __restrict__ cnt) {
  __shared__ float tile[CDIM][65];
  const int b  = blockIdx.x >> 7;          // 128 tiles per batch
  const int t0 = (blockIdx.x & 127) << 6;  // 64 t per tile
  const int tid = threadIdx.x;
  if (blockIdx.x == 0 && tid < BN * NSTEPS) cnt[tid] = 0;  // replaces memset dispatch
#pragma unroll
  for (int i = 0; i < 4; ++i) {
    int fid = tid + i * 256;                // 0..1023
    int cc = fid >> 4, qt = (fid & 15) << 2;
    float4 vv = *(const float4*)(x + ((size_t)b * CDIM + cc) * TOT + t0 + qt);
    tile[cc][qt + 0] = vv.x; tile[cc][qt + 1] = vv.y;
    tile[cc][qt + 2] = vv.z; tile[cc][qt + 3] = vv.w;
  }
  __syncthreads();
#pragma unroll
  for (int i = 0; i < 4; ++i) {
    int fid = tid + i * 256;
    int tt = fid >> 4, qc = (fid & 15) << 2;
    float4 vv = make_float4(tile[qc + 0][tt], tile[qc + 1][tt],
                            tile[qc + 2][tt], tile[qc + 3][tt]);
    *(float4*)(xt + ((size_t)b * TOT + t0 + tt) * CDIM + qc) = vv;
  }
}

__global__ __launch_bounds__(256, 2) void walk_kernel(
    const float* __restrict__ xt, const int* __restrict__ adj, const int* __restrict__ cur,
    const float* __restrict__ agent_w, const float* __restrict__ agent_gamma,
    const float* __restrict__ agent_beta, const float* __restrict__ agent_mean,
    const float* __restrict__ agent_var, const float* __restrict__ mom_w,
    const float* __restrict__ mom_gamma, const float* __restrict__ mom_beta,
    const float* __restrict__ mom_mean, const float* __restrict__ mom_var,
    float* __restrict__ out, float* __restrict__ sbuf, unsigned int* __restrict__ cnt) {
  __shared__ float lds_out[WPB * WSTRIDE];  // per-thread-private slots, no barrier needed
  const int tid  = threadIdx.x;
  const int lane = tid & 63;
  const int wv   = tid >> 6;
  const int g    = lane >> 4;   // group within wave (one walker per group)
  const int L    = lane & 15;   // lane within group
  const int b     = (blockIdx.x & 7) + (((blockIdx.x >> 8) & 1) << 3);
  const int chunk = (blockIdx.x >> 3) & 31;
  const int w     = wv * 4 + g;                // walker slot within block
  const int n     = chunk * WPB + w;           // walker index within batch
  const int c0    = L << 2;                    // channels c0..c0+3

  const float4 aw1  = *(const float4*)(agent_w + c0);
  const float4 aw2  = *(const float4*)(agent_w + 64 + c0);
  const float4 mw0a = *(const float4*)(mom_w + c0);
  const float4 mw0b = *(const float4*)(mom_w + 64 + c0);
  const float4 mw1a = *(const float4*)(mom_w + 128 + c0);
  const float4 mw1b = *(const float4*)(mom_w + 192 + c0);
  const float amean  = agent_mean[0];
  const float abeta  = agent_beta[0];
  const float ainv   = agent_gamma[0] / sqrtf(agent_var[0] + 1e-5f);
  const float m0mean = mom_mean[0], m1mean = mom_mean[1];
  const float m0inv  = mom_gamma[0] / sqrtf(mom_var[0] + 1e-5f);
  const float m1inv  = mom_gamma[1] / sqrtf(mom_var[1] + 1e-5f);
  const float m0beta = mom_beta[0], m1beta = mom_beta[1];

  const float* xb   = xt + (size_t)b * TOT * CDIM;
  const int*   adjb = adj + (size_t)b * TOT * KNB;
  float*       lout = lds_out + w * WSTRIDE;

  int t = cur[b * CN + n];
  float4 pf = *(const float4*)(xb + (size_t)t * CDIM + c0);
  float4 cf = pf;
  float4 u  = make_float4(0.f, 0.f, 0.f, 0.f);

  // prefetch step-0 neighborhood
  int    idx[KNB];
  float4 nv[KNB];
  {
    const int4* arow = (const int4*)(adjb + (size_t)t * KNB);
    int4 q0 = arow[0], q1 = arow[1], q2 = arow[2], q3 = arow[3], q4 = arow[4];
    int tmp[KNB] = {q0.x, q0.y, q0.z, q0.w, q1.x, q1.y, q1.z, q1.w,
                    q2.x, q2.y, q2.z, q2.w, q3.x, q3.y, q3.z, q3.w,
                    q4.x, q4.y, q4.z, q4.w};
#pragma unroll
    for (int j = 0; j < KNB; ++j) idx[j] = tmp[j];
#pragma unroll
    for (int j = 0; j < KNB; ++j)
      nv[j] = *(const float4*)(xb + (size_t)idx[j] * CDIM + c0);
  }

#pragma unroll 1
  for (int s = 0; s < NSTEPS; ++s) {
    float n1 = 0.f;
    if (s > 0) {
      // ---- batch barrier (raw s_barrier: keeps prefetch loads in flight) ----
      __builtin_amdgcn_s_barrier();
      unsigned int* c = cnt + (b * NSTEPS + s);
      if (tid == 0) {
        __hip_atomic_fetch_add(c, 1u, __ATOMIC_RELAXED, __HIP_MEMORY_SCOPE_AGENT);
        while (__hip_atomic_load(c, __ATOMIC_RELAXED, __HIP_MEMORY_SCOPE_AGENT) < BPB) {
          __builtin_amdgcn_s_sleep(2);
        }
      }
      __builtin_amdgcn_s_barrier();
      asm volatile("" ::: "memory");
      const float* sb = sbuf + ((size_t)(b * NSTEPS + s) << 10);
      float A0 = __hip_atomic_load(sb + 2 * n, __ATOMIC_RELAXED, __HIP_MEMORY_SCOPE_AGENT);
      float A1 = __hip_atomic_load(sb + 2 * n + 1, __ATOMIC_RELAXED, __HIP_MEMORY_SCOPE_AGENT);
      pf.x = A0 * cf.x + A1 * pf.x;
      pf.y = A0 * cf.y + A1 * pf.y;
      pf.z = A0 * cf.z + A1 * pf.z;
      pf.w = A0 * cf.w + A1 * pf.w;
      u.x = cf.x - pf.x; u.y = cf.y - pf.y; u.z = cf.z - pf.z; u.w = cf.w - pf.w;
      n1 = sqrtf(gred16(u.x * u.x + u.y * u.y + u.z * u.z + u.w * u.w));
    }
    float pw = gred16(pf.x * aw2.x + pf.y * aw2.y + pf.z * aw2.z + pf.w * aw2.w);

    float  bestp = -3.4e38f;
    int    bestt = 0;
    float4 bestv = make_float4(0.f, 0.f, 0.f, 0.f);
#pragma unroll
    for (int j = 0; j < KNB; ++j) {
      const float4 v = nv[j];
      float pa = v.x * aw1.x + v.y * aw1.y + v.z * aw1.z + v.w * aw1.w;
      float su = 0.f, sn = 0.f;
      if (s > 0) {
        float tx = v.x - cf.x, ty = v.y - cf.y, tz = v.z - cf.z, tw = v.w - cf.w;
        su = tx * u.x + ty * u.y + tz * u.z + tw * u.w;
        sn = tx * tx + ty * ty + tz * tz + tw * tw;
      }
      pa = gred16(pa);
      float logit = (pa + pw - amean) * ainv + abeta;
      float p;
      if (s > 0) {
        su = gred16(su);
        sn = gred16(sn);
        float den  = fmaxf(n1 * sqrtf(sn), 1e-8f);
        float cosv = su / den;
        float dfac = fminf(fmaxf(1.0f + cosv, 0.0f), 1.0f);
        p = logit * dfac;
      } else {
        p = logit;
      }
      if (p > bestp) { bestp = p; bestt = idx[j]; bestv = v; }
    }
    cf = bestv;
    t  = bestt;
    // stash into LDS out-buffer (private slots; written once to HBM at the end)
    lout[(c0 + 0) * 9 + s] = cf.x;
    lout[(c0 + 1) * 9 + s] = cf.y;
    lout[(c0 + 2) * 9 + s] = cf.z;
    lout[(c0 + 3) * 9 + s] = cf.w;

    if (s < NSTEPS - 1) {
      // ---- momentum logits for step s+1 (uses cf=cur_feat(s), pf=pre_feat(s)) ----
      float p0 = cf.x * mw0a.x + cf.y * mw0a.y + cf.z * mw0a.z + cf.w * mw0a.w +
                 pf.x * mw0b.x + pf.y * mw0b.y + pf.z * mw0b.z + pf.w * mw0b.w;
      float p1 = cf.x * mw1a.x + cf.y * mw1a.y + cf.z * mw1a.z + cf.w * mw1a.w +
                 pf.x * mw1b.x + pf.y * mw1b.y + pf.z * mw1b.z + pf.w * mw1b.w;
      p0 = gred16(p0);
      p1 = gred16(p1);
      float mlog0 = (p0 - m0mean) * m0inv + m0beta;
      float mlog1 = (p1 - m1mean) * m1inv + m1beta;
      float mx = fmaxf(mlog0, mlog1);
      float e0 = expf(mlog0 - mx), e1 = expf(mlog1 - mx);
      float sinv = 1.0f / (e0 + e1);
      float* sb = sbuf + ((size_t)(b * NSTEPS + s + 1) << 10);
      if (L == 0) {
        __hip_atomic_store(sb + n, e0 * sinv, __ATOMIC_RELAXED, __HIP_MEMORY_SCOPE_AGENT);
        __hip_atomic_store(sb + CN + n, e1 * sinv, __ATOMIC_RELAXED, __HIP_MEMORY_SCOPE_AGENT);
      }
      // release: publish stores at coherence point before this wave reaches the barrier
      asm volatile("s_waitcnt vmcnt(0)" ::: "memory");
      // ---- prefetch step-(s+1) neighborhood; latency overlaps the barrier spin ----
      const int4* arow = (const int4*)(adjb + (size_t)t * KNB);
      int4 q0 = arow[0], q1 = arow[1], q2 = arow[2], q3 = arow[3], q4 = arow[4];
      int tmp[KNB] = {q0.x, q0.y, q0.z, q0.w, q1.x, q1.y, q1.z, q1.w,
                      q2.x, q2.y, q2.z, q2.w, q3.x, q3.y, q3.z, q3.w,
                      q4.x, q4.y, q4.z, q4.w};
#pragma unroll
      for (int j = 0; j < KNB; ++j) idx[j] = tmp[j];
#pragma unroll
      for (int j = 0; j < KNB; ++j)
        nv[j] = *(const float4*)(xb + (size_t)idx[j] * CDIM + c0);
    }
  }

  // ---- single coalesced write phase: out[b][c][n][0..7] = 32B per (c,n) ----
#pragma unroll
  for (int e = 0; e < 4; ++e) {
    const float* src = lout + (c0 + e) * 9;
    float4 w0 = make_float4(src[0], src[1], src[2], src[3]);
    float4 w1 = make_float4(src[4], src[5], src[6], src[7]);
    float* op = out + (((size_t)(b * CDIM + c0 + e) * CN) + n) * NSTEPS;
    *(float4*)(op)     = w0;
    *(float4*)(op + 4) = w1;
  }
}

extern "C" void kernel_launch(void* const* d_in, const int* in_sizes, int n_in,
                              void* d_out, int out_size, void* d_ws, size_t ws_size,
                              hipStream_t stream) {
  (void)in_sizes; (void)n_in; (void)out_size; (void)ws_size;
  const float* x          = (const float*)d_in[1];
  const int*   adj        = (const int*)d_in[2];
  const int*   cur        = (const int*)d_in[3];
  const float* agent_w    = (const float*)d_in[4];
  const float* agent_gamma= (const float*)d_in[5];
  const float* agent_beta = (const float*)d_in[6];
  const float* agent_mean = (const float*)d_in[7];
  const float* agent_var  = (const float*)d_in[8];
  const float* mom_w      = (const float*)d_in[9];
  const float* mom_gamma  = (const float*)d_in[10];
  const float* mom_beta   = (const float*)d_in[11];
  const float* mom_mean   = (const float*)d_in[12];
  const float* mom_var    = (const float*)d_in[13];
  float* out = (float*)d_out;

  char* ws = (char*)d_ws;
  const size_t xt_bytes   = (size_t)BN * TOT * CDIM * sizeof(float);   // 33.5 MB
  const size_t sbuf_bytes = (size_t)BN * NSTEPS * 2 * CN * sizeof(float);
  float*        xt   = (float*)ws;
  float*        sbuf = (float*)(ws + xt_bytes);
  unsigned int* cnt  = (unsigned int*)(ws + xt_bytes + sbuf_bytes);

  transpose_x<<<BN * (TOT / 64), 256, 0, stream>>>(x, xt, cnt);
  walk_kernel<<<BN * BPB, 256, 0, stream>>>(xt, adj, cur, agent_w, agent_gamma, agent_beta,
                                            agent_mean, agent_var, mom_w, mom_gamma, mom_beta,
                                            mom_mean, mom_var, out, sbuf, cnt);
}

// Round 4
// 186.224 us; speedup vs baseline: 5.3549x; 1.1252x over previous
//
#include <hip/hip_runtime.h>
#include <cmath>

#define BN 16
#define CDIM 64
#define TOT 8192
#define KNB 20
#define CN 512
#define NSTEPS 8
#define WPB 16           // walkers per block (4 waves x 4 groups)
#define BPB 32           // blocks per batch (CN / WPB)
#define WSTRIDE 577      // per-walker LDS out-buffer stride (64*9 + 1 pad)
#define CNTSTRIDE 32     // uints per barrier counter (128B line, no false sharing)

// DPP add: v += lane-permuted(v). All patterns stay within the 16-lane row.
template <int CTRL>
__device__ __forceinline__ float dpp_add(float v) {
  int o = __builtin_amdgcn_update_dpp(0, __float_as_int(v), CTRL, 0xF, 0xF, true);
  return v + __int_as_float(o);
}

// butterfly sum across the 16-lane group — pure VALU, bitwise identical tree
__device__ __forceinline__ float gred16(float v) {
  v = dpp_add<0xB1>(v);   // quad_perm(1,0,3,2)  == xor 1
  v = dpp_add<0x4E>(v);   // quad_perm(2,3,0,1)  == xor 2
  v = dpp_add<0x141>(v);  // row_half_mirror     == xor 4
  v = dpp_add<0x140>(v);  // row_mirror          == xor 8
  return v;
}

__global__ __launch_bounds__(256) void transpose_x(const float* __restrict__ x,
                                                   float* __restrict__ xt,
                                                   unsigned int* __restrict__ cnt) {
  __shared__ float tile[CDIM][65];
  const int b  = blockIdx.x >> 7;          // 128 tiles per batch
  const int t0 = (blockIdx.x & 127) << 6;  // 64 t per tile
  const int tid = threadIdx.x;
  if (blockIdx.x < BN) cnt[blockIdx.x * 256 + tid] = 0;  // 4096 uints total
#pragma unroll
  for (int i = 0; i < 4; ++i) {
    int fid = tid + i * 256;                // 0..1023
    int cc = fid >> 4, qt = (fid & 15) << 2;
    float4 vv = *(const float4*)(x + ((size_t)b * CDIM + cc) * TOT + t0 + qt);
    tile[cc][qt + 0] = vv.x; tile[cc][qt + 1] = vv.y;
    tile[cc][qt + 2] = vv.z; tile[cc][qt + 3] = vv.w;
  }
  __syncthreads();
#pragma unroll
  for (int i = 0; i < 4; ++i) {
    int fid = tid + i * 256;
    int tt = fid >> 4, qc = (fid & 15) << 2;
    float4 vv = make_float4(tile[qc + 0][tt], tile[qc + 1][tt],
                            tile[qc + 2][tt], tile[qc + 3][tt]);
    *(float4*)(xt + ((size_t)b * TOT + t0 + tt) * CDIM + qc) = vv;
  }
}

__global__ __launch_bounds__(256, 2) void walk_kernel(
    const float* __restrict__ xt, const int* __restrict__ adj, const int* __restrict__ cur,
    const float* __restrict__ agent_w, const float* __restrict__ agent_gamma,
    const float* __restrict__ agent_beta, const float* __restrict__ agent_mean,
    const float* __restrict__ agent_var, const float* __restrict__ mom_w,
    const float* __restrict__ mom_gamma, const float* __restrict__ mom_beta,
    const float* __restrict__ mom_mean, const float* __restrict__ mom_var,
    float* __restrict__ out, float* __restrict__ sbuf, unsigned int* __restrict__ cnt) {
  __shared__ float lds_out[WPB * WSTRIDE];  // per-thread-private slots
  const int tid  = threadIdx.x;
  const int lane = tid & 63;
  const int wv   = tid >> 6;
  const int g    = lane >> 4;   // group within wave (one walker per group)
  const int L    = lane & 15;   // lane within group
  const int b     = (blockIdx.x & 7) + (((blockIdx.x >> 8) & 1) << 3);
  const int chunk = (blockIdx.x >> 3) & 31;
  const int w     = wv * 4 + g;                // walker slot within block
  const int n     = chunk * WPB + w;           // walker index within batch
  const int c0    = L << 2;                    // channels c0..c0+3

  const float4 aw1  = *(const float4*)(agent_w + c0);
  const float4 aw2  = *(const float4*)(agent_w + 64 + c0);
  const float4 mw0a = *(const float4*)(mom_w + c0);
  const float4 mw0b = *(const float4*)(mom_w + 64 + c0);
  const float4 mw1a = *(const float4*)(mom_w + 128 + c0);
  const float4 mw1b = *(const float4*)(mom_w + 192 + c0);
  const float amean  = agent_mean[0];
  const float abeta  = agent_beta[0];
  const float ainv   = agent_gamma[0] / sqrtf(agent_var[0] + 1e-5f);
  const float m0mean = mom_mean[0], m1mean = mom_mean[1];
  const float m0inv  = mom_gamma[0] / sqrtf(mom_var[0] + 1e-5f);
  const float m1inv  = mom_gamma[1] / sqrtf(mom_var[1] + 1e-5f);
  const float m0beta = mom_beta[0], m1beta = mom_beta[1];

  const float* xb   = xt + (size_t)b * TOT * CDIM;
  const int*   adjb = adj + (size_t)b * TOT * KNB;
  float*       lout = lds_out + w * WSTRIDE;

  int t = cur[b * CN + n];
  float4 pf = *(const float4*)(xb + (size_t)t * CDIM + c0);
  float4 cf = pf;
  float4 u  = make_float4(0.f, 0.f, 0.f, 0.f);

  // prefetch step-0 neighborhood (values land in VGPRs and stay there)
  int    idx[KNB];
  float4 nv[KNB];
  {
    const int4* arow = (const int4*)(adjb + (size_t)t * KNB);
    int4 q0 = arow[0], q1 = arow[1], q2 = arow[2], q3 = arow[3], q4 = arow[4];
    int tmp[KNB] = {q0.x, q0.y, q0.z, q0.w, q1.x, q1.y, q1.z, q1.w,
                    q2.x, q2.y, q2.z, q2.w, q3.x, q3.y, q3.z, q3.w,
                    q4.x, q4.y, q4.z, q4.w};
#pragma unroll
    for (int j = 0; j < KNB; ++j) idx[j] = tmp[j];
#pragma unroll
    for (int j = 0; j < KNB; ++j)
      nv[j] = *(const float4*)(xb + (size_t)idx[j] * CDIM + c0);
    asm volatile("s_waitcnt vmcnt(0)" ::: "memory");  // pin loads + results here
  }

#pragma unroll 1
  for (int s = 0; s < NSTEPS; ++s) {
    float n1 = 0.f;
    if (s > 0) {
      // ---- batch barrier: all loads already drained, nothing in flight ----
      __builtin_amdgcn_s_barrier();
      unsigned int* c = cnt + (size_t)(b * NSTEPS + s) * CNTSTRIDE;
      if (tid == 0) {
        __hip_atomic_fetch_add(c, 1u, __ATOMIC_RELAXED, __HIP_MEMORY_SCOPE_AGENT);
        while (__hip_atomic_load(c, __ATOMIC_RELAXED, __HIP_MEMORY_SCOPE_AGENT) < BPB) {
          __builtin_amdgcn_s_sleep(2);
        }
      }
      __builtin_amdgcn_s_barrier();
      asm volatile("" ::: "memory");
      const float* sb = sbuf + ((size_t)(b * NSTEPS + s) << 10);
      float A0 = __hip_atomic_load(sb + 2 * n, __ATOMIC_RELAXED, __HIP_MEMORY_SCOPE_AGENT);
      float A1 = __hip_atomic_load(sb + 2 * n + 1, __ATOMIC_RELAXED, __HIP_MEMORY_SCOPE_AGENT);
      pf.x = A0 * cf.x + A1 * pf.x;
      pf.y = A0 * cf.y + A1 * pf.y;
      pf.z = A0 * cf.z + A1 * pf.z;
      pf.w = A0 * cf.w + A1 * pf.w;
      u.x = cf.x - pf.x; u.y = cf.y - pf.y; u.z = cf.z - pf.z; u.w = cf.w - pf.w;
      n1 = sqrtf(gred16(u.x * u.x + u.y * u.y + u.z * u.z + u.w * u.w));
    }
    float pw = gred16(pf.x * aw2.x + pf.y * aw2.y + pf.z * aw2.z + pf.w * aw2.w);

    float  bestp = -3.4e38f;
    int    bestt = 0;
    float4 bestv = make_float4(0.f, 0.f, 0.f, 0.f);
#pragma unroll
    for (int j = 0; j < KNB; ++j) {
      const float4 v = nv[j];
      float pa = v.x * aw1.x + v.y * aw1.y + v.z * aw1.z + v.w * aw1.w;
      float su = 0.f, sn = 0.f;
      if (s > 0) {
        float tx = v.x - cf.x, ty = v.y - cf.y, tz = v.z - cf.z, tw = v.w - cf.w;
        su = tx * u.x + ty * u.y + tz * u.z + tw * u.w;
        sn = tx * tx + ty * ty + tz * tz + tw * tw;
      }
      pa = gred16(pa);
      float logit = (pa + pw - amean) * ainv + abeta;
      float p;
      if (s > 0) {
        su = gred16(su);
        sn = gred16(sn);
        float den  = fmaxf(n1 * sqrtf(sn), 1e-8f);
        float cosv = su / den;
        float dfac = fminf(fmaxf(1.0f + cosv, 0.0f), 1.0f);
        p = logit * dfac;
      } else {
        p = logit;
      }
      if (p > bestp) { bestp = p; bestt = idx[j]; bestv = v; }
    }
    cf = bestv;
    t  = bestt;
    // stash into LDS out-buffer (private slots; written once to HBM at the end)
    lout[(c0 + 0) * 9 + s] = cf.x;
    lout[(c0 + 1) * 9 + s] = cf.y;
    lout[(c0 + 2) * 9 + s] = cf.z;
    lout[(c0 + 3) * 9 + s] = cf.w;

    if (s < NSTEPS - 1) {
      // ---- momentum logits for step s+1 (uses cf=cur_feat(s), pf=pre_feat(s)) ----
      float p0 = cf.x * mw0a.x + cf.y * mw0a.y + cf.z * mw0a.z + cf.w * mw0a.w +
                 pf.x * mw0b.x + pf.y * mw0b.y + pf.z * mw0b.z + pf.w * mw0b.w;
      float p1 = cf.x * mw1a.x + cf.y * mw1a.y + cf.z * mw1a.z + cf.w * mw1a.w +
                 pf.x * mw1b.x + pf.y * mw1b.y + pf.z * mw1b.z + pf.w * mw1b.w;
      p0 = gred16(p0);
      p1 = gred16(p1);
      float mlog0 = (p0 - m0mean) * m0inv + m0beta;
      float mlog1 = (p1 - m1mean) * m1inv + m1beta;
      float mx = fmaxf(mlog0, mlog1);
      float e0 = expf(mlog0 - mx), e1 = expf(mlog1 - mx);
      float sinv = 1.0f / (e0 + e1);
      float* sb = sbuf + ((size_t)(b * NSTEPS + s + 1) << 10);
      if (L == 0) {
        __hip_atomic_store(sb + n, e0 * sinv, __ATOMIC_RELAXED, __HIP_MEMORY_SCOPE_AGENT);
        __hip_atomic_store(sb + CN + n, e1 * sinv, __ATOMIC_RELAXED, __HIP_MEMORY_SCOPE_AGENT);
      }
      // ---- prefetch step-(s+1) neighborhood, then drain EVERYTHING before
      //      the barrier: publish visible, gather results pinned in VGPRs ----
      const int4* arow = (const int4*)(adjb + (size_t)t * KNB);
      int4 q0 = arow[0], q1 = arow[1], q2 = arow[2], q3 = arow[3], q4 = arow[4];
      int tmp[KNB] = {q0.x, q0.y, q0.z, q0.w, q1.x, q1.y, q1.z, q1.w,
                      q2.x, q2.y, q2.z, q2.w, q3.x, q3.y, q3.z, q3.w,
                      q4.x, q4.y, q4.z, q4.w};
#pragma unroll
      for (int j = 0; j < KNB; ++j) idx[j] = tmp[j];
#pragma unroll
      for (int j = 0; j < KNB; ++j)
        nv[j] = *(const float4*)(xb + (size_t)idx[j] * CDIM + c0);
      asm volatile("s_waitcnt vmcnt(0)" ::: "memory");
    }
  }

  // ---- single coalesced write phase: out[b][c][n][0..7] = 32B per (c,n) ----
#pragma unroll
  for (int e = 0; e < 4; ++e) {
    const float* src = lout + (c0 + e) * 9;
    float4 w0 = make_float4(src[0], src[1], src[2], src[3]);
    float4 w1 = make_float4(src[4], src[5], src[6], src[7]);
    float* op = out + (((size_t)(b * CDIM + c0 + e) * CN) + n) * NSTEPS;
    *(float4*)(op)     = w0;
    *(float4*)(op + 4) = w1;
  }
}

extern "C" void kernel_launch(void* const* d_in, const int* in_sizes, int n_in,
                              void* d_out, int out_size, void* d_ws, size_t ws_size,
                              hipStream_t stream) {
  (void)in_sizes; (void)n_in; (void)out_size; (void)ws_size;
  const float* x          = (const float*)d_in[1];
  const int*   adj        = (const int*)d_in[2];
  const int*   cur        = (const int*)d_in[3];
  const float* agent_w    = (const float*)d_in[4];
  const float* agent_gamma= (const float*)d_in[5];
  const float* agent_beta = (const float*)d_in[6];
  const float* agent_mean = (const float*)d_in[7];
  const float* agent_var  = (const float*)d_in[8];
  const float* mom_w      = (const float*)d_in[9];
  const float* mom_gamma  = (const float*)d_in[10];
  const float* mom_beta   = (const float*)d_in[11];
  const float* mom_mean   = (const float*)d_in[12];
  const float* mom_var    = (const float*)d_in[13];
  float* out = (float*)d_out;

  char* ws = (char*)d_ws;
  const size_t xt_bytes   = (size_t)BN * TOT * CDIM * sizeof(float);   // 33.5 MB
  const size_t sbuf_bytes = (size_t)BN * NSTEPS * 2 * CN * sizeof(float);
  float*        xt   = (float*)ws;
  float*        sbuf = (float*)(ws + xt_bytes);
  unsigned int* cnt  = (unsigned int*)(ws + xt_bytes + sbuf_bytes);

  transpose_x<<<BN * (TOT / 64), 256, 0, stream>>>(x, xt, cnt);
  walk_kernel<<<BN * BPB, 256, 0, stream>>>(xt, adj, cur, agent_w, agent_gamma, agent_beta,
                                            agent_mean, agent_var, mom_w, mom_gamma, mom_beta,
                                            mom_mean, mom_var, out, sbuf, cnt);
}

// Round 5
// 185.609 us; speedup vs baseline: 5.3726x; 1.0033x over previous
//
#include <hip/hip_runtime.h>
#include <cmath>

#define BN 16
#define CDIM 64
#define TOT 8192
#define KNB 20
#define CN 512
#define NSTEPS 8
#define WPB 16           // walkers per block (4 waves x 4 groups)
#define BPB 32           // blocks per batch (CN / WPB)
#define WSTRIDE 577      // per-walker LDS out-buffer stride (64*9 + 1 pad)
#define CNTSTRIDE 32     // uints per barrier counter (128B line, no false sharing)

typedef float vf4 __attribute__((ext_vector_type(4)));

// DPP add: v += lane-permuted(v). All patterns stay within the 16-lane row.
template <int CTRL>
__device__ __forceinline__ float dpp_add(float v) {
  int o = __builtin_amdgcn_update_dpp(0, __float_as_int(v), CTRL, 0xF, 0xF, true);
  return v + __int_as_float(o);
}

// butterfly sum across the 16-lane group — pure VALU, bitwise identical tree
__device__ __forceinline__ float gred16(float v) {
  v = dpp_add<0xB1>(v);   // quad_perm(1,0,3,2)  == xor 1
  v = dpp_add<0x4E>(v);   // quad_perm(2,3,0,1)  == xor 2
  v = dpp_add<0x141>(v);  // row_half_mirror     == xor 4
  v = dpp_add<0x140>(v);  // row_mirror          == xor 8
  return v;
}

__global__ __launch_bounds__(256) void transpose_x(const float* __restrict__ x,
                                                   float* __restrict__ xt,
                                                   unsigned int* __restrict__ cnt) {
  __shared__ float tile[CDIM][65];
  const int b  = blockIdx.x >> 7;          // 128 tiles per batch
  const int t0 = (blockIdx.x & 127) << 6;  // 64 t per tile
  const int tid = threadIdx.x;
  if (blockIdx.x < BN) cnt[blockIdx.x * 256 + tid] = 0;  // 4096 uints total
#pragma unroll
  for (int i = 0; i < 4; ++i) {
    int fid = tid + i * 256;                // 0..1023
    int cc = fid >> 4, qt = (fid & 15) << 2;
    float4 vv = *(const float4*)(x + ((size_t)b * CDIM + cc) * TOT + t0 + qt);
    tile[cc][qt + 0] = vv.x; tile[cc][qt + 1] = vv.y;
    tile[cc][qt + 2] = vv.z; tile[cc][qt + 3] = vv.w;
  }
  __syncthreads();
#pragma unroll
  for (int i = 0; i < 4; ++i) {
    int fid = tid + i * 256;
    int tt = fid >> 4, qc = (fid & 15) << 2;
    float4 vv = make_float4(tile[qc + 0][tt], tile[qc + 1][tt],
                            tile[qc + 2][tt], tile[qc + 3][tt]);
    *(float4*)(xt + ((size_t)b * TOT + t0 + tt) * CDIM + qc) = vv;
  }
}

// opaque gather: result pinned in VGPRs, cannot be sunk/rematerialized
#define GATHER(J, TJ)                                                        \
  {                                                                          \
    i##J = (TJ);                                                             \
    const float* p##J = xb + (size_t)i##J * CDIM + c0;                       \
    asm volatile("global_load_dwordx4 %0, %1, off" : "=v"(v##J) : "v"(p##J)); \
  }

#define SCORE(J)                                                             \
  {                                                                          \
    const vf4 v = v##J;                                                      \
    float pa = v.x * aw1.x + v.y * aw1.y + v.z * aw1.z + v.w * aw1.w;        \
    float su = 0.f, sn = 0.f;                                                \
    if (s > 0) {                                                             \
      float tx = v.x - cf.x, ty = v.y - cf.y, tz = v.z - cf.z,               \
            tw = v.w - cf.w;                                                 \
      su = tx * u.x + ty * u.y + tz * u.z + tw * u.w;                        \
      sn = tx * tx + ty * ty + tz * tz + tw * tw;                            \
    }                                                                        \
    pa = gred16(pa);                                                         \
    float logit = (pa + pw - amean) * ainv + abeta;                          \
    float p;                                                                 \
    if (s > 0) {                                                             \
      su = gred16(su);                                                       \
      sn = gred16(sn);                                                       \
      float den  = fmaxf(n1 * sqrtf(sn), 1e-8f);                             \
      float cosv = su / den;                                                 \
      float dfac = fminf(fmaxf(1.0f + cosv, 0.0f), 1.0f);                    \
      p = logit * dfac;                                                      \
    } else {                                                                 \
      p = logit;                                                             \
    }                                                                        \
    if (p > bestp) { bestp = p; bestt = i##J; bestv = v; }                   \
  }

__global__ __launch_bounds__(256, 2) void walk_kernel(
    const float* __restrict__ xt, const int* __restrict__ adj, const int* __restrict__ cur,
    const float* __restrict__ agent_w, const float* __restrict__ agent_gamma,
    const float* __restrict__ agent_beta, const float* __restrict__ agent_mean,
    const float* __restrict__ agent_var, const float* __restrict__ mom_w,
    const float* __restrict__ mom_gamma, const float* __restrict__ mom_beta,
    const float* __restrict__ mom_mean, const float* __restrict__ mom_var,
    float* __restrict__ out, float* __restrict__ sbuf, unsigned int* __restrict__ cnt) {
  __shared__ float lds_out[WPB * WSTRIDE];  // per-thread-private slots
  const int tid  = threadIdx.x;
  const int lane = tid & 63;
  const int wv   = tid >> 6;
  const int g    = lane >> 4;   // group within wave (one walker per group)
  const int L    = lane & 15;   // lane within group
  const int b     = (blockIdx.x & 7) + (((blockIdx.x >> 8) & 1) << 3);
  const int chunk = (blockIdx.x >> 3) & 31;
  const int w     = wv * 4 + g;                // walker slot within block
  const int n     = chunk * WPB + w;           // walker index within batch
  const int c0    = L << 2;                    // channels c0..c0+3

  const vf4 aw1  = *(const vf4*)(agent_w + c0);
  const vf4 aw2  = *(const vf4*)(agent_w + 64 + c0);
  const vf4 mw0a = *(const vf4*)(mom_w + c0);
  const vf4 mw0b = *(const vf4*)(mom_w + 64 + c0);
  const vf4 mw1a = *(const vf4*)(mom_w + 128 + c0);
  const vf4 mw1b = *(const vf4*)(mom_w + 192 + c0);
  const float amean  = agent_mean[0];
  const float abeta  = agent_beta[0];
  const float ainv   = agent_gamma[0] / sqrtf(agent_var[0] + 1e-5f);
  const float m0mean = mom_mean[0], m1mean = mom_mean[1];
  const float m0inv  = mom_gamma[0] / sqrtf(mom_var[0] + 1e-5f);
  const float m1inv  = mom_gamma[1] / sqrtf(mom_var[1] + 1e-5f);
  const float m0beta = mom_beta[0], m1beta = mom_beta[1];

  const float* xb   = xt + (size_t)b * TOT * CDIM;
  const int*   adjb = adj + (size_t)b * TOT * KNB;
  float*       lout = lds_out + w * WSTRIDE;

  int t = cur[b * CN + n];
  vf4 pf = *(const vf4*)(xb + (size_t)t * CDIM + c0);
  vf4 cf = pf;
  vf4 u  = (vf4){0.f, 0.f, 0.f, 0.f};

  int i0,i1,i2,i3,i4,i5,i6,i7,i8,i9,i10,i11,i12,i13,i14,i15,i16,i17,i18,i19;
  vf4 v0,v1,v2,v3,v4,v5,v6,v7,v8,v9,v10,v11,v12,v13,v14,v15,v16,v17,v18,v19;

  {
    const int4* arow = (const int4*)(adjb + (size_t)t * KNB);
    int4 q0 = arow[0], q1 = arow[1], q2 = arow[2], q3 = arow[3], q4 = arow[4];
    GATHER(0,  q0.x) GATHER(1,  q0.y) GATHER(2,  q0.z) GATHER(3,  q0.w)
    GATHER(4,  q1.x) GATHER(5,  q1.y) GATHER(6,  q1.z) GATHER(7,  q1.w)
    GATHER(8,  q2.x) GATHER(9,  q2.y) GATHER(10, q2.z) GATHER(11, q2.w)
    GATHER(12, q3.x) GATHER(13, q3.y) GATHER(14, q3.z) GATHER(15, q3.w)
    GATHER(16, q4.x) GATHER(17, q4.y) GATHER(18, q4.z) GATHER(19, q4.w)
    asm volatile("s_waitcnt vmcnt(0)" ::: "memory");
  }

#pragma unroll 1
  for (int s = 0; s < NSTEPS; ++s) {
    float n1 = 0.f;
    if (s > 0) {
      // ---- batch barrier: nothing in flight (drained pre-barrier) ----
      __builtin_amdgcn_s_barrier();
      unsigned int* c = cnt + (size_t)(b * NSTEPS + s) * CNTSTRIDE;
      if (tid == 0) {
        __hip_atomic_fetch_add(c, 1u, __ATOMIC_RELAXED, __HIP_MEMORY_SCOPE_AGENT);
        while (__hip_atomic_load(c, __ATOMIC_RELAXED, __HIP_MEMORY_SCOPE_AGENT) < BPB) {
          __builtin_amdgcn_s_sleep(2);
        }
      }
      __builtin_amdgcn_s_barrier();
      asm volatile("" ::: "memory");
      const float* sb = sbuf + ((size_t)(b * NSTEPS + s) << 10);
      float A0 = __hip_atomic_load(sb + 2 * n, __ATOMIC_RELAXED, __HIP_MEMORY_SCOPE_AGENT);
      float A1 = __hip_atomic_load(sb + 2 * n + 1, __ATOMIC_RELAXED, __HIP_MEMORY_SCOPE_AGENT);
      pf.x = A0 * cf.x + A1 * pf.x;
      pf.y = A0 * cf.y + A1 * pf.y;
      pf.z = A0 * cf.z + A1 * pf.z;
      pf.w = A0 * cf.w + A1 * pf.w;
      u.x = cf.x - pf.x; u.y = cf.y - pf.y; u.z = cf.z - pf.z; u.w = cf.w - pf.w;
      n1 = sqrtf(gred16(u.x * u.x + u.y * u.y + u.z * u.z + u.w * u.w));
    }
    float pw = gred16(pf.x * aw2.x + pf.y * aw2.y + pf.z * aw2.z + pf.w * aw2.w);

    float bestp = -3.4e38f;
    int   bestt = 0;
    vf4   bestv = (vf4){0.f, 0.f, 0.f, 0.f};
    SCORE(0)  SCORE(1)  SCORE(2)  SCORE(3)  SCORE(4)
    SCORE(5)  SCORE(6)  SCORE(7)  SCORE(8)  SCORE(9)
    SCORE(10) SCORE(11) SCORE(12) SCORE(13) SCORE(14)
    SCORE(15) SCORE(16) SCORE(17) SCORE(18) SCORE(19)
    cf = bestv;
    t  = bestt;
    // stash into LDS out-buffer (private slots; written once to HBM at the end)
    lout[(c0 + 0) * 9 + s] = cf.x;
    lout[(c0 + 1) * 9 + s] = cf.y;
    lout[(c0 + 2) * 9 + s] = cf.z;
    lout[(c0 + 3) * 9 + s] = cf.w;

    if (s < NSTEPS - 1) {
      // ---- momentum logits for step s+1 (uses cf=cur_feat(s), pf=pre_feat(s)) ----
      float p0 = cf.x * mw0a.x + cf.y * mw0a.y + cf.z * mw0a.z + cf.w * mw0a.w +
                 pf.x * mw0b.x + pf.y * mw0b.y + pf.z * mw0b.z + pf.w * mw0b.w;
      float p1 = cf.x * mw1a.x + cf.y * mw1a.y + cf.z * mw1a.z + cf.w * mw1a.w +
                 pf.x * mw1b.x + pf.y * mw1b.y + pf.z * mw1b.z + pf.w * mw1b.w;
      p0 = gred16(p0);
      p1 = gred16(p1);
      float mlog0 = (p0 - m0mean) * m0inv + m0beta;
      float mlog1 = (p1 - m1mean) * m1inv + m1beta;
      float mx = fmaxf(mlog0, mlog1);
      float e0 = expf(mlog0 - mx), e1 = expf(mlog1 - mx);
      float sinv = 1.0f / (e0 + e1);
      float* sb = sbuf + ((size_t)(b * NSTEPS + s + 1) << 10);
      if (L == 0) {
        __hip_atomic_store(sb + n, e0 * sinv, __ATOMIC_RELAXED, __HIP_MEMORY_SCOPE_AGENT);
        __hip_atomic_store(sb + CN + n, e1 * sinv, __ATOMIC_RELAXED, __HIP_MEMORY_SCOPE_AGENT);
      }
      // ---- opaque prefetch of step-(s+1) neighborhood; drain EVERYTHING
      //      (publish store + gathers) before the barrier ----
      const int4* arow = (const int4*)(adjb + (size_t)t * KNB);
      int4 q0 = arow[0], q1 = arow[1], q2 = arow[2], q3 = arow[3], q4 = arow[4];
      GATHER(0,  q0.x) GATHER(1,  q0.y) GATHER(2,  q0.z) GATHER(3,  q0.w)
      GATHER(4,  q1.x) GATHER(5,  q1.y) GATHER(6,  q1.z) GATHER(7,  q1.w)
      GATHER(8,  q2.x) GATHER(9,  q2.y) GATHER(10, q2.z) GATHER(11, q2.w)
      GATHER(12, q3.x) GATHER(13, q3.y) GATHER(14, q3.z) GATHER(15, q3.w)
      GATHER(16, q4.x) GATHER(17, q4.y) GATHER(18, q4.z) GATHER(19, q4.w)
      asm volatile("s_waitcnt vmcnt(0)" ::: "memory");
    }
  }

  // ---- single coalesced write phase: out[b][c][n][0..7] = 32B per (c,n) ----
#pragma unroll
  for (int e = 0; e < 4; ++e) {
    const float* src = lout + (c0 + e) * 9;
    float4 w0 = make_float4(src[0], src[1], src[2], src[3]);
    float4 w1 = make_float4(src[4], src[5], src[6], src[7]);
    float* op = out + (((size_t)(b * CDIM + c0 + e) * CN) + n) * NSTEPS;
    *(float4*)(op)     = w0;
    *(float4*)(op + 4) = w1;
  }
}

extern "C" void kernel_launch(void* const* d_in, const int* in_sizes, int n_in,
                              void* d_out, int out_size, void* d_ws, size_t ws_size,
                              hipStream_t stream) {
  (void)in_sizes; (void)n_in; (void)out_size; (void)ws_size;
  const float* x          = (const float*)d_in[1];
  const int*   adj        = (const int*)d_in[2];
  const int*   cur        = (const int*)d_in[3];
  const float* agent_w    = (const float*)d_in[4];
  const float* agent_gamma= (const float*)d_in[5];
  const float* agent_beta = (const float*)d_in[6];
  const float* agent_mean = (const float*)d_in[7];
  const float* agent_var  = (const float*)d_in[8];
  const float* mom_w      = (const float*)d_in[9];
  const float* mom_gamma  = (const float*)d_in[10];
  const float* mom_beta   = (const float*)d_in[11];
  const float* mom_mean   = (const float*)d_in[12];
  const float* mom_var    = (const float*)d_in[13];
  float* out = (float*)d_out;

  char* ws = (char*)d_ws;
  const size_t xt_bytes   = (size_t)BN * TOT * CDIM * sizeof(float);   // 33.5 MB
  const size_t sbuf_bytes = (size_t)BN * NSTEPS * 2 * CN * sizeof(float);
  float*        xt   = (float*)ws;
  float*        sbuf = (float*)(ws + xt_bytes);
  unsigned int* cnt  = (unsigned int*)(ws + xt_bytes + sbuf_bytes);

  transpose_x<<<BN * (TOT / 64), 256, 0, stream>>>(x, xt, cnt);
  walk_kernel<<<BN * BPB, 256, 0, stream>>>(xt, adj, cur, agent_w, agent_gamma, agent_beta,
                                            agent_mean, agent_var, mom_w, mom_gamma, mom_beta,
                                            mom_mean, mom_var, out, sbuf, cnt);
}

// Round 6
// 163.363 us; speedup vs baseline: 6.1042x; 1.1362x over previous
//
#include <hip/hip_runtime.h>
#include <cmath>

#define BN 16
#define CDIM 64
#define TOT 8192
#define KNB 20
#define CN 512
#define NSTEPS 8
#define WPB 16           // walkers per block (4 waves x 4 groups)
#define BPB 32           // blocks per batch (CN / WPB)
#define WSTRIDE 577      // per-walker LDS out-buffer stride (64*9 + 1 pad)
#define FLAGSTRIDE 32    // uints per flag (128B line, no false sharing)

typedef float vf4 __attribute__((ext_vector_type(4)));

// shared between kernels so pa gets the identical mul/fma contraction
__device__ __forceinline__ float dot4(float a, float b, float c, float d,
                                      float wa, float wb, float wc, float wd) {
  return a * wa + b * wb + c * wc + d * wd;
}

// DPP add: v += lane-permuted(v). All patterns stay within the 16-lane row.
template <int CTRL>
__device__ __forceinline__ float dpp_add(float v) {
  int o = __builtin_amdgcn_update_dpp(0, __float_as_int(v), CTRL, 0xF, 0xF, true);
  return v + __int_as_float(o);
}

// butterfly sum across the 16-lane group — pure VALU; balanced binary tree
__device__ __forceinline__ float gred16(float v) {
  v = dpp_add<0xB1>(v);   // quad_perm(1,0,3,2)  == xor 1
  v = dpp_add<0x4E>(v);   // quad_perm(2,3,0,1)  == xor 2
  v = dpp_add<0x141>(v);  // row_half_mirror     == xor 4 (post-stage2)
  v = dpp_add<0x140>(v);  // row_mirror          == xor 8 (post-stage3)
  return v;
}

__global__ __launch_bounds__(256) void transpose_x(const float* __restrict__ x,
                                                   const float* __restrict__ agent_w,
                                                   float* __restrict__ xt,
                                                   float* __restrict__ pa,
                                                   unsigned int* __restrict__ flags) {
  __shared__ float tile[CDIM][65];
  const int b  = blockIdx.x >> 7;          // 128 tiles per batch
  const int t0 = (blockIdx.x & 127) << 6;  // 64 t per tile
  const int tid = threadIdx.x;
  if (blockIdx.x < 64) flags[blockIdx.x * 256 + tid] = 0;  // 16K uints total
#pragma unroll
  for (int i = 0; i < 4; ++i) {
    int fid = tid + i * 256;                // 0..1023
    int cc = fid >> 4, qt = (fid & 15) << 2;
    float4 vv = *(const float4*)(x + ((size_t)b * CDIM + cc) * TOT + t0 + qt);
    tile[cc][qt + 0] = vv.x; tile[cc][qt + 1] = vv.y;
    tile[cc][qt + 2] = vv.z; tile[cc][qt + 3] = vv.w;
  }
  __syncthreads();
#pragma unroll
  for (int i = 0; i < 4; ++i) {
    int fid = tid + i * 256;
    int tt = fid >> 4, qc = (fid & 15) << 2;
    float4 vv = make_float4(tile[qc + 0][tt], tile[qc + 1][tt],
                            tile[qc + 2][tt], tile[qc + 3][tt]);
    *(float4*)(xt + ((size_t)b * TOT + t0 + tt) * CDIM + qc) = vv;
  }
  // pa[t] = dot(x_t, agent_w[0:64]) with the walker's exact tree:
  // per-16ch dot4 chunks, then the gred16 balanced binary tree.
  if (tid < 64) {
    const int tt = tid;
    float q[16];
#pragma unroll
    for (int l = 0; l < 16; ++l)
      q[l] = dot4(tile[4 * l][tt], tile[4 * l + 1][tt],
                  tile[4 * l + 2][tt], tile[4 * l + 3][tt],
                  agent_w[4 * l], agent_w[4 * l + 1],
                  agent_w[4 * l + 2], agent_w[4 * l + 3]);
    float sA = (q[0] + q[1]) + (q[2] + q[3]);
    float sB = (q[4] + q[5]) + (q[6] + q[7]);
    float sC = (q[8] + q[9]) + (q[10] + q[11]);
    float sD = (q[12] + q[13]) + (q[14] + q[15]);
    pa[(size_t)b * TOT + t0 + tt] = (sA + sB) + (sC + sD);
  }
}

__global__ __launch_bounds__(256, 2) void walk_kernel(
    const float* __restrict__ xt, const int* __restrict__ adj, const int* __restrict__ cur,
    const float* __restrict__ agent_w, const float* __restrict__ agent_gamma,
    const float* __restrict__ agent_beta, const float* __restrict__ agent_mean,
    const float* __restrict__ agent_var, const float* __restrict__ mom_w,
    const float* __restrict__ mom_gamma, const float* __restrict__ mom_beta,
    const float* __restrict__ mom_mean, const float* __restrict__ mom_var,
    const float* __restrict__ pa,
    float* __restrict__ out, float* __restrict__ sbuf, unsigned int* __restrict__ flags) {
  __shared__ float lds_out[WPB * WSTRIDE];  // per-thread-private slots
  const int tid  = threadIdx.x;
  const int lane = tid & 63;
  const int wv   = tid >> 6;
  const int g    = lane >> 4;   // group within wave (one walker per group)
  const int L    = lane & 15;   // lane within group
  const int b     = (blockIdx.x & 7) + (((blockIdx.x >> 8) & 1) << 3);
  const int chunk = (blockIdx.x >> 3) & 31;   // block index within batch
  const int w     = wv * 4 + g;               // walker slot within block
  const int n     = chunk * WPB + w;          // walker index within batch
  const int c0    = L << 2;                   // channels c0..c0+3
  // producer blocks for the momentum-coeff scramble: 2*(chunk%16), +1
  const int P0    = (chunk & 15) << 1;

  const vf4 aw2  = *(const vf4*)(agent_w + 64 + c0);
  const vf4 mw0a = *(const vf4*)(mom_w + c0);
  const vf4 mw0b = *(const vf4*)(mom_w + 64 + c0);
  const vf4 mw1a = *(const vf4*)(mom_w + 128 + c0);
  const vf4 mw1b = *(const vf4*)(mom_w + 192 + c0);
  const float amean  = agent_mean[0];
  const float abeta  = agent_beta[0];
  const float ainv   = agent_gamma[0] / sqrtf(agent_var[0] + 1e-5f);
  const float m0mean = mom_mean[0], m1mean = mom_mean[1];
  const float m0inv  = mom_gamma[0] / sqrtf(mom_var[0] + 1e-5f);
  const float m1inv  = mom_gamma[1] / sqrtf(mom_var[1] + 1e-5f);
  const float m0beta = mom_beta[0], m1beta = mom_beta[1];

  const float* xb   = xt + (size_t)b * TOT * CDIM;
  const float* pab  = pa + (size_t)b * TOT;
  const int*   adjb = adj + (size_t)b * TOT * KNB;
  float*       lout = lds_out + w * WSTRIDE;
  unsigned int* myflag = flags + ((size_t)b * BPB + chunk) * FLAGSTRIDE;

  int t = cur[b * CN + n];
  vf4 pf = *(const vf4*)(xb + (size_t)t * CDIM + c0);
  vf4 cf = pf;
  vf4 u  = (vf4){0.f, 0.f, 0.f, 0.f};

  int   idx[KNB];
  vf4   nv[KNB];
  float pav[KNB];
  {
    const int4* arow = (const int4*)(adjb + (size_t)t * KNB);
    int4 q0 = arow[0], q1 = arow[1], q2 = arow[2], q3 = arow[3], q4 = arow[4];
    int tmp[KNB] = {q0.x, q0.y, q0.z, q0.w, q1.x, q1.y, q1.z, q1.w,
                    q2.x, q2.y, q2.z, q2.w, q3.x, q3.y, q3.z, q3.w,
                    q4.x, q4.y, q4.z, q4.w};
#pragma unroll
    for (int j = 0; j < KNB; ++j) idx[j] = tmp[j];
#pragma unroll
    for (int j = 0; j < KNB; ++j) {
      nv[j]  = *(const vf4*)(xb + (size_t)idx[j] * CDIM + c0);
      pav[j] = pab[idx[j]];
    }
  }

#pragma unroll 1
  for (int s = 0; s < NSTEPS; ++s) {
    float n1 = 0.f;
    if (s > 0) {
      // producers already flagged (bottom of previous iteration); read coeffs
      const float* sb = sbuf + ((size_t)(b * NSTEPS + s) << 10);
      float A0 = __hip_atomic_load(sb + 2 * n, __ATOMIC_RELAXED, __HIP_MEMORY_SCOPE_AGENT);
      float A1 = __hip_atomic_load(sb + 2 * n + 1, __ATOMIC_RELAXED, __HIP_MEMORY_SCOPE_AGENT);
      pf.x = A0 * cf.x + A1 * pf.x;
      pf.y = A0 * cf.y + A1 * pf.y;
      pf.z = A0 * cf.z + A1 * pf.z;
      pf.w = A0 * cf.w + A1 * pf.w;
      u.x = cf.x - pf.x; u.y = cf.y - pf.y; u.z = cf.z - pf.z; u.w = cf.w - pf.w;
      n1 = sqrtf(gred16(u.x * u.x + u.y * u.y + u.z * u.z + u.w * u.w));
    }
    float pw = gred16(pf.x * aw2.x + pf.y * aw2.y + pf.z * aw2.z + pf.w * aw2.w);

    float bestp = -3.4e38f;
    int   bestt = 0;
    vf4   bestv = (vf4){0.f, 0.f, 0.f, 0.f};
#pragma unroll
    for (int j = 0; j < KNB; ++j) {
      const vf4 v = nv[j];
      float logit = (pav[j] + pw - amean) * ainv + abeta;   // pa precomputed per node
      float p;
      if (s > 0) {
        float tx = v.x - cf.x, ty = v.y - cf.y, tz = v.z - cf.z, tw = v.w - cf.w;
        float su = tx * u.x + ty * u.y + tz * u.z + tw * u.w;
        float sn = tx * tx + ty * ty + tz * tz + tw * tw;
        su = gred16(su);
        sn = gred16(sn);
        float den  = fmaxf(n1 * sqrtf(sn), 1e-8f);
        float cosv = su * __builtin_amdgcn_rcpf(den);       // rcp+mul replaces IEEE div
        float dfac = fminf(fmaxf(1.0f + cosv, 0.0f), 1.0f);
        p = logit * dfac;
      } else {
        p = logit;
      }
      if (p > bestp) { bestp = p; bestt = idx[j]; bestv = v; }
    }
    cf = bestv;
    t  = bestt;
    lout[(c0 + 0) * 9 + s] = cf.x;
    lout[(c0 + 1) * 9 + s] = cf.y;
    lout[(c0 + 2) * 9 + s] = cf.z;
    lout[(c0 + 3) * 9 + s] = cf.w;

    if (s < NSTEPS - 1) {
      // ---- momentum logits for step s+1 ----
      float p0 = cf.x * mw0a.x + cf.y * mw0a.y + cf.z * mw0a.z + cf.w * mw0a.w +
                 pf.x * mw0b.x + pf.y * mw0b.y + pf.z * mw0b.z + pf.w * mw0b.w;
      float p1 = cf.x * mw1a.x + cf.y * mw1a.y + cf.z * mw1a.z + cf.w * mw1a.w +
                 pf.x * mw1b.x + pf.y * mw1b.y + pf.z * mw1b.z + pf.w * mw1b.w;
      p0 = gred16(p0);
      p1 = gred16(p1);
      float mlog0 = (p0 - m0mean) * m0inv + m0beta;
      float mlog1 = (p1 - m1mean) * m1inv + m1beta;
      float mx = fmaxf(mlog0, mlog1);
      float e0 = expf(mlog0 - mx), e1 = expf(mlog1 - mx);
      float sinv = 1.0f / (e0 + e1);
      float* sb = sbuf + ((size_t)(b * NSTEPS + s + 1) << 10);
      if (L == 0) {
        __hip_atomic_store(sb + n, e0 * sinv, __ATOMIC_RELAXED, __HIP_MEMORY_SCOPE_AGENT);
        __hip_atomic_store(sb + CN + n, e1 * sinv, __ATOMIC_RELAXED, __HIP_MEMORY_SCOPE_AGENT);
      }
      asm volatile("s_waitcnt vmcnt(0)" ::: "memory");  // S stores at coherence point
      __builtin_amdgcn_s_barrier();                     // whole block's S published
      if (tid == 0)
        __hip_atomic_store(myflag, (unsigned)(s + 1), __ATOMIC_RELAXED, __HIP_MEMORY_SCOPE_AGENT);
      // ---- prefetch next neighborhood (overlaps the flag wait) ----
      const int4* arow = (const int4*)(adjb + (size_t)t * KNB);
      int4 q0 = arow[0], q1 = arow[1], q2 = arow[2], q3 = arow[3], q4 = arow[4];
      int tmp[KNB] = {q0.x, q0.y, q0.z, q0.w, q1.x, q1.y, q1.z, q1.w,
                      q2.x, q2.y, q2.z, q2.w, q3.x, q3.y, q3.z, q3.w,
                      q4.x, q4.y, q4.z, q4.w};
#pragma unroll
      for (int j = 0; j < KNB; ++j) idx[j] = tmp[j];
#pragma unroll
      for (int j = 0; j < KNB; ++j) {
        nv[j]  = *(const vf4*)(xb + (size_t)idx[j] * CDIM + c0);
        pav[j] = pab[idx[j]];
      }
      // ---- wait on our TWO producer blocks only (pairwise dependency) ----
      if (lane == 0 && wv < 2) {
        const unsigned int* pflag = flags + ((size_t)b * BPB + P0 + wv) * FLAGSTRIDE;
        while (__hip_atomic_load(pflag, __ATOMIC_RELAXED, __HIP_MEMORY_SCOPE_AGENT) <
               (unsigned)(s + 1)) {
          __builtin_amdgcn_s_sleep(2);
        }
      }
      __builtin_amdgcn_s_barrier();
      asm volatile("" ::: "memory");
    }
  }

  // ---- single coalesced write phase: out[b][c][n][0..7] = 32B per (c,n) ----
#pragma unroll
  for (int e = 0; e < 4; ++e) {
    const float* src = lout + (c0 + e) * 9;
    float4 w0 = make_float4(src[0], src[1], src[2], src[3]);
    float4 w1 = make_float4(src[4], src[5], src[6], src[7]);
    float* op = out + (((size_t)(b * CDIM + c0 + e) * CN) + n) * NSTEPS;
    *(float4*)(op)     = w0;
    *(float4*)(op + 4) = w1;
  }
}

extern "C" void kernel_launch(void* const* d_in, const int* in_sizes, int n_in,
                              void* d_out, int out_size, void* d_ws, size_t ws_size,
                              hipStream_t stream) {
  (void)in_sizes; (void)n_in; (void)out_size; (void)ws_size;
  const float* x          = (const float*)d_in[1];
  const int*   adj        = (const int*)d_in[2];
  const int*   cur        = (const int*)d_in[3];
  const float* agent_w    = (const float*)d_in[4];
  const float* agent_gamma= (const float*)d_in[5];
  const float* agent_beta = (const float*)d_in[6];
  const float* agent_mean = (const float*)d_in[7];
  const float* agent_var  = (const float*)d_in[8];
  const float* mom_w      = (const float*)d_in[9];
  const float* mom_gamma  = (const float*)d_in[10];
  const float* mom_beta   = (const float*)d_in[11];
  const float* mom_mean   = (const float*)d_in[12];
  const float* mom_var    = (const float*)d_in[13];
  float* out = (float*)d_out;

  char* ws = (char*)d_ws;
  const size_t xt_bytes   = (size_t)BN * TOT * CDIM * sizeof(float);       // 33.5 MB
  const size_t sbuf_bytes = (size_t)BN * NSTEPS * 2 * CN * sizeof(float);  // 512 KB
  const size_t pa_bytes   = (size_t)BN * TOT * sizeof(float);              // 512 KB
  float*        xt    = (float*)ws;
  float*        sbuf  = (float*)(ws + xt_bytes);
  float*        pab   = (float*)(ws + xt_bytes + sbuf_bytes);
  unsigned int* flags = (unsigned int*)(ws + xt_bytes + sbuf_bytes + pa_bytes);

  transpose_x<<<BN * (TOT / 64), 256, 0, stream>>>(x, agent_w, xt, pab, flags);
  walk_kernel<<<BN * BPB, 256, 0, stream>>>(xt, adj, cur, agent_w, agent_gamma, agent_beta,
                                            agent_mean, agent_var, mom_w, mom_gamma, mom_beta,
                                            mom_mean, mom_var, pab, out, sbuf, flags);
}

// Round 7
// 163.105 us; speedup vs baseline: 6.1139x; 1.0016x over previous
//
#include <hip/hip_runtime.h>
#include <cmath>

#define BN 16
#define CDIM 64
#define TOT 8192
#define KNB 20
#define CN 512
#define NSTEPS 8
#define WPB 16           // walkers per block (4 waves x 4 groups)
#define BPB 32           // blocks per batch (CN / WPB)
#define WSTRIDE 577      // per-walker LDS out-buffer stride (64*9 + 1 pad)
#define FLAGSTRIDE 32    // uints per flag line (128B, no false sharing)
#define MAGIC 0x5A17ECE1u  // != 0xAAAAAAAA poison, != 0 — write-once slots need no init

typedef float vf4 __attribute__((ext_vector_type(4)));

// shared contraction so pa (precompute) == walker's exact FMA tree
__device__ __forceinline__ float dot4(float a, float b, float c, float d,
                                      float wa, float wb, float wc, float wd) {
  return a * wa + b * wb + c * wc + d * wd;
}

template <int CTRL>
__device__ __forceinline__ float dpp_add(float v) {
  int o = __builtin_amdgcn_update_dpp(0, __float_as_int(v), CTRL, 0xF, 0xF, true);
  return v + __int_as_float(o);
}

// butterfly sum across the 16-lane group — pure VALU; balanced binary tree
__device__ __forceinline__ float gred16(float v) {
  v = dpp_add<0xB1>(v);   // quad_perm xor1
  v = dpp_add<0x4E>(v);   // quad_perm xor2
  v = dpp_add<0x141>(v);  // row_half_mirror (xor4)
  v = dpp_add<0x140>(v);  // row_mirror (xor8)
  return v;
}

__global__ __launch_bounds__(256, 2) void walk_kernel(
    const float* __restrict__ x, const int* __restrict__ adj, const int* __restrict__ cur,
    const float* __restrict__ agent_w, const float* __restrict__ agent_gamma,
    const float* __restrict__ agent_beta, const float* __restrict__ agent_mean,
    const float* __restrict__ agent_var, const float* __restrict__ mom_w,
    const float* __restrict__ mom_gamma, const float* __restrict__ mom_beta,
    const float* __restrict__ mom_mean, const float* __restrict__ mom_var,
    float* __restrict__ xt, float* __restrict__ pa,
    float* __restrict__ out, float* __restrict__ sbuf, unsigned int* __restrict__ flags) {
  __shared__ float lds_out[WPB * WSTRIDE];  // walk-phase out buffer; aliased as tile below
  const int tid  = threadIdx.x;
  const int lane = tid & 63;
  const int wv   = tid >> 6;
  const int g    = lane >> 4;
  const int L    = lane & 15;
  const int b     = (blockIdx.x & 7) + (((blockIdx.x >> 8) & 1) << 3);
  const int chunk = (blockIdx.x >> 3) & 31;
  const int w     = wv * 4 + g;
  const int n     = chunk * WPB + w;
  const int c0    = L << 2;
  const int P0    = (chunk & 15) << 1;  // producer blocks: 2*(chunk%16), +1

  unsigned int* myflag = flags + ((size_t)b * BPB + chunk) * FLAGSTRIDE;

  // ================= phase 1: transpose + pa (fused, sc1 -> MALL) =================
  {
    float (*tile)[65] = (float (*)[65])lds_out;  // 64*65*4 = 16.6 KB < 36.9 KB
#pragma unroll 1
    for (int i = 0; i < 4; ++i) {
      const int t0 = ((chunk << 2) + i) << 6;
#pragma unroll
      for (int k = 0; k < 4; ++k) {
        int fid = tid + k * 256;
        int cc = fid >> 4, qt = (fid & 15) << 2;
        float4 vv = *(const float4*)(x + ((size_t)b * CDIM + cc) * TOT + t0 + qt);
        tile[cc][qt + 0] = vv.x; tile[cc][qt + 1] = vv.y;
        tile[cc][qt + 2] = vv.z; tile[cc][qt + 3] = vv.w;
      }
      __syncthreads();
#pragma unroll
      for (int k = 0; k < 4; ++k) {
        int fid = tid + k * 256;
        int tt = fid >> 4, qc = (fid & 15) << 2;
        vf4 vv = {tile[qc + 0][tt], tile[qc + 1][tt], tile[qc + 2][tt], tile[qc + 3][tt]};
        float* dst = xt + ((size_t)b * TOT + t0 + tt) * CDIM + qc;
        // device-scope store: lands at MALL so any XCD's reader sees it post-flag
        asm volatile("global_store_dwordx4 %0, %1, off sc0 sc1" :: "v"(dst), "v"(vv) : "memory");
      }
      if (tid < 64) {
        const int tt = tid;
        float q[16];
#pragma unroll
        for (int l = 0; l < 16; ++l)
          q[l] = dot4(tile[4 * l][tt], tile[4 * l + 1][tt],
                      tile[4 * l + 2][tt], tile[4 * l + 3][tt],
                      agent_w[4 * l], agent_w[4 * l + 1],
                      agent_w[4 * l + 2], agent_w[4 * l + 3]);
        float sA = (q[0] + q[1]) + (q[2] + q[3]);
        float sB = (q[4] + q[5]) + (q[6] + q[7]);
        float sC = (q[8] + q[9]) + (q[10] + q[11]);
        float sD = (q[12] + q[13]) + (q[14] + q[15]);
        __hip_atomic_store(pa + (size_t)b * TOT + t0 + tt, (sA + sB) + (sC + sD),
                           __ATOMIC_RELAXED, __HIP_MEMORY_SCOPE_AGENT);
      }
      __syncthreads();
    }
    asm volatile("s_waitcnt vmcnt(0)" ::: "memory");  // all sc1 stores at MALL
    __builtin_amdgcn_s_barrier();
    if (tid == 0)
      __hip_atomic_store(myflag + 8, MAGIC, __ATOMIC_RELAXED, __HIP_MEMORY_SCOPE_AGENT);
    if (tid < BPB) {  // wait for all 32 blocks of this batch
      const unsigned int* f = flags + ((size_t)b * BPB + tid) * FLAGSTRIDE + 8;
      while (__hip_atomic_load(f, __ATOMIC_RELAXED, __HIP_MEMORY_SCOPE_AGENT) != MAGIC)
        __builtin_amdgcn_s_sleep(2);
    }
    __builtin_amdgcn_s_barrier();
    asm volatile("" ::: "memory");
  }

  // ================= phase 2: the walk =================
  const vf4 aw2  = *(const vf4*)(agent_w + 64 + c0);
  const vf4 mw0a = *(const vf4*)(mom_w + c0);
  const vf4 mw0b = *(const vf4*)(mom_w + 64 + c0);
  const vf4 mw1a = *(const vf4*)(mom_w + 128 + c0);
  const vf4 mw1b = *(const vf4*)(mom_w + 192 + c0);
  const float amean  = agent_mean[0];
  const float abeta  = agent_beta[0];
  const float ainv   = agent_gamma[0] / sqrtf(agent_var[0] + 1e-5f);
  const float m0mean = mom_mean[0], m1mean = mom_mean[1];
  const float m0inv  = mom_gamma[0] / sqrtf(mom_var[0] + 1e-5f);
  const float m1inv  = mom_gamma[1] / sqrtf(mom_var[1] + 1e-5f);
  const float m0beta = mom_beta[0], m1beta = mom_beta[1];

  const float* xb   = xt + (size_t)b * TOT * CDIM;
  const float* pab  = pa + (size_t)b * TOT;
  const int*   adjb = adj + (size_t)b * TOT * KNB;
  float*       lout = lds_out + w * WSTRIDE;

  int t = cur[b * CN + n];
  vf4 pf = *(const vf4*)(xb + (size_t)t * CDIM + c0);
  vf4 cf = pf;
  vf4 u  = (vf4){0.f, 0.f, 0.f, 0.f};

  int   idx[KNB];
  vf4   nv[KNB];
  float pav[KNB];
  {
    const int4* arow = (const int4*)(adjb + (size_t)t * KNB);
    int4 q0 = arow[0], q1 = arow[1], q2 = arow[2], q3 = arow[3], q4 = arow[4];
    int tmp[KNB] = {q0.x, q0.y, q0.z, q0.w, q1.x, q1.y, q1.z, q1.w,
                    q2.x, q2.y, q2.z, q2.w, q3.x, q3.y, q3.z, q3.w,
                    q4.x, q4.y, q4.z, q4.w};
#pragma unroll
    for (int j = 0; j < KNB; ++j) idx[j] = tmp[j];
#pragma unroll
    for (int j = 0; j < KNB; ++j) {
      nv[j]  = *(const vf4*)(xb + (size_t)idx[j] * CDIM + c0);
      pav[j] = pab[idx[j]];
    }
  }

#pragma unroll 1
  for (int s = 0; s < NSTEPS; ++s) {
    float n1 = 0.f;
    if (s > 0) {
      const float* sb = sbuf + ((size_t)(b * NSTEPS + s) << 10);
      float A0 = __hip_atomic_load(sb + 2 * n, __ATOMIC_RELAXED, __HIP_MEMORY_SCOPE_AGENT);
      float A1 = __hip_atomic_load(sb + 2 * n + 1, __ATOMIC_RELAXED, __HIP_MEMORY_SCOPE_AGENT);
      pf.x = A0 * cf.x + A1 * pf.x;
      pf.y = A0 * cf.y + A1 * pf.y;
      pf.z = A0 * cf.z + A1 * pf.z;
      pf.w = A0 * cf.w + A1 * pf.w;
      u.x = cf.x - pf.x; u.y = cf.y - pf.y; u.z = cf.z - pf.z; u.w = cf.w - pf.w;
      n1 = sqrtf(gred16(u.x * u.x + u.y * u.y + u.z * u.z + u.w * u.w));
    }
    float pw = gred16(pf.x * aw2.x + pf.y * aw2.y + pf.z * aw2.z + pf.w * aw2.w);

    float bestp = -3.4e38f;
    int   bestt = 0;
    vf4   bestv = (vf4){0.f, 0.f, 0.f, 0.f};
#pragma unroll
    for (int j = 0; j < KNB; ++j) {
      const vf4 v = nv[j];
      float logit = (pav[j] + pw - amean) * ainv + abeta;
      float p;
      if (s > 0) {
        float tx = v.x - cf.x, ty = v.y - cf.y, tz = v.z - cf.z, tw = v.w - cf.w;
        float su = tx * u.x + ty * u.y + tz * u.z + tw * u.w;
        float sn = tx * tx + ty * ty + tz * tz + tw * tw;
        su = gred16(su);
        sn = gred16(sn);
        float den  = fmaxf(n1 * sqrtf(sn), 1e-8f);
        float cosv = su * __builtin_amdgcn_rcpf(den);
        float dfac = fminf(fmaxf(1.0f + cosv, 0.0f), 1.0f);
        p = logit * dfac;
      } else {
        p = logit;
      }
      if (p > bestp) { bestp = p; bestt = idx[j]; bestv = v; }
    }
    cf = bestv;
    t  = bestt;
    lout[(c0 + 0) * 9 + s] = cf.x;
    lout[(c0 + 1) * 9 + s] = cf.y;
    lout[(c0 + 2) * 9 + s] = cf.z;
    lout[(c0 + 3) * 9 + s] = cf.w;

    if (s < NSTEPS - 1) {
      float p0 = cf.x * mw0a.x + cf.y * mw0a.y + cf.z * mw0a.z + cf.w * mw0a.w +
                 pf.x * mw0b.x + pf.y * mw0b.y + pf.z * mw0b.z + pf.w * mw0b.w;
      float p1 = cf.x * mw1a.x + cf.y * mw1a.y + cf.z * mw1a.z + cf.w * mw1a.w +
                 pf.x * mw1b.x + pf.y * mw1b.y + pf.z * mw1b.z + pf.w * mw1b.w;
      p0 = gred16(p0);
      p1 = gred16(p1);
      float mlog0 = (p0 - m0mean) * m0inv + m0beta;
      float mlog1 = (p1 - m1mean) * m1inv + m1beta;
      float mx = fmaxf(mlog0, mlog1);
      float e0 = expf(mlog0 - mx), e1 = expf(mlog1 - mx);
      float sinv = 1.0f / (e0 + e1);
      float* sb = sbuf + ((size_t)(b * NSTEPS + s + 1) << 10);
      if (L == 0) {
        __hip_atomic_store(sb + n, e0 * sinv, __ATOMIC_RELAXED, __HIP_MEMORY_SCOPE_AGENT);
        __hip_atomic_store(sb + CN + n, e1 * sinv, __ATOMIC_RELAXED, __HIP_MEMORY_SCOPE_AGENT);
      }
      asm volatile("s_waitcnt vmcnt(0)" ::: "memory");  // S at coherence point
      __builtin_amdgcn_s_barrier();                     // whole block published
      if (tid == 0)
        __hip_atomic_store(myflag + (s + 1), MAGIC, __ATOMIC_RELAXED, __HIP_MEMORY_SCOPE_AGENT);
      // prefetch next neighborhood (overlaps producer-flag wait)
      const int4* arow = (const int4*)(adjb + (size_t)t * KNB);
      int4 q0 = arow[0], q1 = arow[1], q2 = arow[2], q3 = arow[3], q4 = arow[4];
      int tmp[KNB] = {q0.x, q0.y, q0.z, q0.w, q1.x, q1.y, q1.z, q1.w,
                      q2.x, q2.y, q2.z, q2.w, q3.x, q3.y, q3.z, q3.w,
                      q4.x, q4.y, q4.z, q4.w};
#pragma unroll
      for (int j = 0; j < KNB; ++j) idx[j] = tmp[j];
#pragma unroll
      for (int j = 0; j < KNB; ++j) {
        nv[j]  = *(const vf4*)(xb + (size_t)idx[j] * CDIM + c0);
        pav[j] = pab[idx[j]];
      }
      // wait on our TWO producer blocks' write-once step slots
      if (lane == 0 && wv < 2) {
        const unsigned int* pflag =
            flags + ((size_t)b * BPB + P0 + wv) * FLAGSTRIDE + (s + 1);
        while (__hip_atomic_load(pflag, __ATOMIC_RELAXED, __HIP_MEMORY_SCOPE_AGENT) != MAGIC)
          __builtin_amdgcn_s_sleep(2);
      }
      __builtin_amdgcn_s_barrier();
      asm volatile("" ::: "memory");
    }
  }

  // single coalesced write phase: out[b][c][n][0..7] = 32B per (c,n)
#pragma unroll
  for (int e = 0; e < 4; ++e) {
    const float* src = lout + (c0 + e) * 9;
    float4 w0 = make_float4(src[0], src[1], src[2], src[3]);
    float4 w1 = make_float4(src[4], src[5], src[6], src[7]);
    float* op = out + (((size_t)(b * CDIM + c0 + e) * CN) + n) * NSTEPS;
    *(float4*)(op)     = w0;
    *(float4*)(op + 4) = w1;
  }
}

extern "C" void kernel_launch(void* const* d_in, const int* in_sizes, int n_in,
                              void* d_out, int out_size, void* d_ws, size_t ws_size,
                              hipStream_t stream) {
  (void)in_sizes; (void)n_in; (void)out_size; (void)ws_size;
  const float* x          = (const float*)d_in[1];
  const int*   adj        = (const int*)d_in[2];
  const int*   cur        = (const int*)d_in[3];
  const float* agent_w    = (const float*)d_in[4];
  const float* agent_gamma= (const float*)d_in[5];
  const float* agent_beta = (const float*)d_in[6];
  const float* agent_mean = (const float*)d_in[7];
  const float* agent_var  = (const float*)d_in[8];
  const float* mom_w      = (const float*)d_in[9];
  const float* mom_gamma  = (const float*)d_in[10];
  const float* mom_beta   = (const float*)d_in[11];
  const float* mom_mean   = (const float*)d_in[12];
  const float* mom_var    = (const float*)d_in[13];
  float* out = (float*)d_out;

  char* ws = (char*)d_ws;
  const size_t xt_bytes   = (size_t)BN * TOT * CDIM * sizeof(float);       // 33.5 MB
  const size_t sbuf_bytes = (size_t)BN * NSTEPS * 2 * CN * sizeof(float);  // 512 KB
  const size_t pa_bytes   = (size_t)BN * TOT * sizeof(float);              // 512 KB
  float*        xt    = (float*)ws;
  float*        sbuf  = (float*)(ws + xt_bytes);
  float*        pab   = (float*)(ws + xt_bytes + sbuf_bytes);
  unsigned int* flags = (unsigned int*)(ws + xt_bytes + sbuf_bytes + pa_bytes);

  walk_kernel<<<BN * BPB, 256, 0, stream>>>(x, adj, cur, agent_w, agent_gamma, agent_beta,
                                            agent_mean, agent_var, mom_w, mom_gamma, mom_beta,
                                            mom_mean, mom_var, xt, pab, out, sbuf, flags);
}